// Round 12
// baseline (552.090 us; speedup 1.0000x reference)
//
#include <hip/hip_runtime.h>
#include <hip/hip_bf16.h>
#include <math.h>

#define D_MODEL 1024
#define SEQ     1024
#define NHEADS  16
#define NKVH    4
#define HDIM    64
#define NEXP    64
#define TOPK    6
#define HEXP    512
#define EPS     1e-5f
#define MAXTILES 120   // <=112 expert tiles + 8 shared-expert tiles

typedef __attribute__((ext_vector_type(8))) short bf16x8;
typedef __attribute__((ext_vector_type(4))) float f32x4;

struct bfrag2 { bf16x8 hi, lo; };
struct f32x8r { float v[8]; };

__device__ __forceinline__ unsigned rne1(float a) {
  union { float f; unsigned u; } x; x.f = a;
  return (x.u + 0x7fffu + ((x.u >> 16) & 1u)) >> 16;
}
__device__ __forceinline__ float frombf(unsigned h) {
  union { float f; unsigned u; } x; x.u = h << 16; return x.f;
}
__device__ __forceinline__ void split_pack(float a, float b, unsigned& hi, unsigned& lo) {
  unsigned ha = rne1(a), hb = rne1(b);
  hi = ha | (hb << 16);
  lo = rne1(a - frombf(ha)) | (rne1(b - frombf(hb)) << 16);
}
__device__ __forceinline__ unsigned pk2bf(float a, float b) {
  return rne1(a) | (rne1(b) << 16);
}

__device__ __forceinline__ f32x4 mfma16(bf16x8 a, bf16x8 b, f32x4 c) {
  return __builtin_amdgcn_mfma_f32_16x16x32_bf16(a, b, c, 0, 0, 0);
}
__device__ __forceinline__ f32x4 mfma_sp(bf16x8 ah, bf16x8 al, const bfrag2& b, f32x4 c) {
  c = mfma16(ah, b.hi, c);
  c = mfma16(ah, b.lo, c);
  c = mfma16(al, b.hi, c);
  return c;
}

__device__ __forceinline__ void barrier_nv() {
  asm volatile("s_waitcnt lgkmcnt(0)" ::: "memory");
  __builtin_amdgcn_s_barrier();
}

// async global->LDS DMA: 16 B/lane; dest = uniform base + lane*16; src per-lane
__device__ __forceinline__ void gload16(const void* g, void* l) {
  __builtin_amdgcn_global_load_lds(
      (const __attribute__((address_space(1))) void*)g,
      (__attribute__((address_space(3))) void*)l, 16, 0, 0);
}

__device__ __forceinline__ f32x8r loadraw8(const float* __restrict__ p, int ld) {
  f32x8r r;
#pragma unroll
  for (int i = 0; i < 8; i++) r.v[i] = p[(size_t)ld * i];
  return r;
}
__device__ __forceinline__ bfrag2 cvt_bf2(const f32x8r& f) {
  union { bf16x8 v; unsigned u[4]; } H, L;
  split_pack(f.v[0], f.v[1], H.u[0], L.u[0]);
  split_pack(f.v[2], f.v[3], H.u[1], L.u[1]);
  split_pack(f.v[4], f.v[5], H.u[2], L.u[2]);
  split_pack(f.v[6], f.v[7], H.u[3], L.u[3]);
  bfrag2 r; r.hi = H.v; r.lo = L.v; return r;
}
template<int RL>
__device__ __forceinline__ bf16x8 bfrag_lds(const ushort* __restrict__ B, int akb, int c) {
  union { bf16x8 v; ushort s[8]; } r;
#pragma unroll
  for (int j = 0; j < 8; j++) r.s[j] = B[(akb + j) * RL + c];
  return r.v;
}

// ---------------- rmsnorm over D=1024 (+ optional bf16 copy) ----------------
__global__ __launch_bounds__(256) void rmsnorm_k(const float* __restrict__ x,
    const float* __restrict__ w, float* __restrict__ out, ushort* __restrict__ outb) {
  int t = blockIdx.x;
  const float4* xr = (const float4*)(x + (size_t)t * D_MODEL);
  float4 v = xr[threadIdx.x];
  float ss = v.x*v.x + v.y*v.y + v.z*v.z + v.w*v.w;
  for (int off = 32; off; off >>= 1) ss += __shfl_xor(ss, off);
  __shared__ float red[4];
  if ((threadIdx.x & 63) == 0) red[threadIdx.x >> 6] = ss;
  __syncthreads();
  float tot = red[0] + red[1] + red[2] + red[3];
  float inv = rsqrtf(tot * (1.f / D_MODEL) + EPS);
  float4 wv = ((const float4*)w)[threadIdx.x];
  float4 o;
  o.x = v.x * inv * wv.x; o.y = v.y * inv * wv.y;
  o.z = v.z * inv * wv.z; o.w = v.w * inv * wv.w;
  ((float4*)(out + (size_t)t * D_MODEL))[threadIdx.x] = o;
  if (outb) {
    uint2 b;
    b.x = pk2bf(o.x, o.y); b.y = pk2bf(o.z, o.w);
    *(uint2*)(outb + (size_t)t * D_MODEL + threadIdx.x * 4) = b;
  }
}

// ---------------- dense split-bf16 MFMA GEMM (r8 structure) ----------------
__global__ __launch_bounds__(256) void mfma_gemm_k(const float* __restrict__ A,
    const float* __restrict__ B, float* __restrict__ C, float* __restrict__ C2,
    const float* __restrict__ resid, int N, int K) {
  __shared__ short Ah[2][16][40];
  __shared__ short Al[2][16][40];
  int bm = blockIdx.y << 4, bn = blockIdx.x << 7;
  int tid = threadIdx.x, wv = tid >> 6, lane = tid & 63;
  int m_ = tid >> 4, k_ = (tid & 15) << 1;
  int arow = lane & 15, akb = (lane >> 4) << 3;
  int c0 = bn + wv * 32 + arow;
  const float* ar = A + (size_t)(bm + m_) * K + k_;
  {
    float2 a0 = *(const float2*)ar;
    unsigned hi, lo; split_pack(a0.x, a0.y, hi, lo);
    *(unsigned*)&Ah[0][m_][k_] = hi;
    *(unsigned*)&Al[0][m_][k_] = lo;
  }
  float2 aO = *(const float2*)(ar + 32);
  float2 aE;
  f32x8r bE0 = loadraw8(B + (size_t)akb * N + c0, N);
  f32x8r bE1 = loadraw8(B + (size_t)akb * N + c0 + 16, N);
  f32x8r bO0 = loadraw8(B + (size_t)(32 + akb) * N + c0, N);
  f32x8r bO1 = loadraw8(B + (size_t)(32 + akb) * N + c0 + 16, N);
  __syncthreads();
  f32x4 acc0 = {0.f,0.f,0.f,0.f}, acc1 = {0.f,0.f,0.f,0.f};
  for (int k0 = 0; k0 < K; k0 += 64) {
    {
      int kp = (k0 + 64 < K) ? k0 + 64 : 0;
      f32x8r n0 = loadraw8(B + (size_t)(kp + akb) * N + c0, N);
      f32x8r n1 = loadraw8(B + (size_t)(kp + akb) * N + c0 + 16, N);
      float2 an = *(const float2*)(ar + kp);
      bfrag2 f0 = cvt_bf2(bE0), f1 = cvt_bf2(bE1);
      bf16x8 ah = *(const bf16x8*)&Ah[0][arow][akb];
      bf16x8 al = *(const bf16x8*)&Al[0][arow][akb];
      acc0 = mfma_sp(ah, al, f0, acc0);
      acc1 = mfma_sp(ah, al, f1, acc1);
      unsigned hi, lo; split_pack(aO.x, aO.y, hi, lo);
      *(unsigned*)&Ah[1][m_][k_] = hi;
      *(unsigned*)&Al[1][m_][k_] = lo;
      barrier_nv();
      bE0 = n0; bE1 = n1; aE = an;
    }
    {
      int kp = (k0 + 96 < K) ? k0 + 96 : 0;
      f32x8r n0 = loadraw8(B + (size_t)(kp + akb) * N + c0, N);
      f32x8r n1 = loadraw8(B + (size_t)(kp + akb) * N + c0 + 16, N);
      float2 an = *(const float2*)(ar + kp);
      bfrag2 f0 = cvt_bf2(bO0), f1 = cvt_bf2(bO1);
      bf16x8 ah = *(const bf16x8*)&Ah[1][arow][akb];
      bf16x8 al = *(const bf16x8*)&Al[1][arow][akb];
      acc0 = mfma_sp(ah, al, f0, acc0);
      acc1 = mfma_sp(ah, al, f1, acc1);
      unsigned hi, lo; split_pack(aE.x, aE.y, hi, lo);
      *(unsigned*)&Ah[0][m_][k_] = hi;
      *(unsigned*)&Al[0][m_][k_] = lo;
      barrier_nv();
      bO0 = n0; bO1 = n1; aO = an;
    }
  }
  int r0 = (lane >> 4) << 2;
#pragma unroll
  for (int ri = 0; ri < 4; ri++) {
    int row = bm + r0 + ri;
    size_t o0 = (size_t)row * N + c0;
    float v0 = acc0[ri], v1 = acc1[ri];
    if (resid) { v0 += resid[o0]; v1 += resid[o0 + 16]; }
    C[o0] = v0; C[o0 + 16] = v1;
    if (C2) { C2[o0] = v0; C2[o0 + 16] = v1; }
  }
}

// ---------------- per-head rmsnorm + RoPE ----------------
__global__ __launch_bounds__(64) void qknorm_rope_k(float* __restrict__ qb,
    float* __restrict__ kb, const float* __restrict__ qw, const float* __restrict__ kw,
    const float* __restrict__ fcos, const float* __restrict__ fsin) {
  int t = blockIdx.x, hid = blockIdx.y, lane = threadIdx.x;
  float* p; const float* w;
  if (hid < NHEADS) { p = qb + (size_t)t * (NHEADS*HDIM) + hid * HDIM; w = qw; }
  else              { p = kb + (size_t)t * (NKVH*HDIM) + (hid - NHEADS) * HDIM; w = kw; }
  float v = p[lane];
  float ss = v * v;
  for (int off = 32; off; off >>= 1) ss += __shfl_xor(ss, off);
  float vn = v * rsqrtf(ss * (1.f / HDIM) + EPS) * w[lane];
  int pi = lane >> 1;
  float c = fcos[t * (HDIM/2) + pi], s = fsin[t * (HDIM/2) + pi];
  float other = __shfl_xor(vn, 1);
  float o = (lane & 1) ? (other * s + vn * c) : (vn * c - other * s);
  p[lane] = o;
}

// ---------------- causal flash attention, bf16 MFMA, GQA 4:1 ----------------
__global__ __launch_bounds__(256) void attn_mfma(const float* __restrict__ qb,
    const float* __restrict__ kb, const float* __restrict__ vb, float* __restrict__ ob) {
  int h = blockIdx.y;
  int qbase = blockIdx.x << 6;
  int kvh = h >> 2;
  int tid = threadIdx.x, wv = tid >> 6, lane = tid & 63;
  __shared__ short Kt[64][72];
  __shared__ short Vt[64][72];
  __shared__ short Pl[4][16][72];
  int arow = lane & 15;
  int akb = (lane >> 4) << 3;
  int kg = lane >> 4;
  int qrow_base = qbase + wv * 16;
  bf16x8 qf[2];
  {
    const float* qp = qb + (size_t)(qrow_base + arow) * (NHEADS*HDIM) + h * HDIM;
#pragma unroll
    for (int c = 0; c < 2; c++) {
      int d0 = akb + c * 32;
      union { bf16x8 v; unsigned u[4]; } r;
#pragma unroll
      for (int j = 0; j < 4; j++) r.u[j] = pk2bf(qp[d0 + 2*j], qp[d0 + 2*j + 1]);
      qf[c] = r.v;
    }
  }
  f32x4 accO[4];
  float m_[4], l_[4];
#pragma unroll
  for (int n = 0; n < 4; n++) { accO[n] = (f32x4){0.f,0.f,0.f,0.f}; m_[n] = -1e30f; l_[n] = 0.f; }
  int ntiles = (qbase >> 6) + 1;
  for (int ti = 0; ti < ntiles; ti++) {
    int ts = ti << 6;
#pragma unroll
    for (int i = 0; i < 16; i++) {
      int flat = tid + i * 256;
      int kk = flat >> 6, dd = flat & 63;
      size_t src = (size_t)(ts + kk) * (NKVH*HDIM) + kvh * HDIM + dd;
      Kt[kk][dd] = (short)rne1(kb[src]);
      Vt[dd][kk] = (short)rne1(vb[src]);
    }
    __syncthreads();
    f32x4 accS[4];
#pragma unroll
    for (int n = 0; n < 4; n++) accS[n] = (f32x4){0.f,0.f,0.f,0.f};
#pragma unroll
    for (int c = 0; c < 2; c++) {
#pragma unroll
      for (int n = 0; n < 4; n++) {
        bf16x8 bf = *(const bf16x8*)&Kt[n*16 + arow][c*32 + akb];
        accS[n] = mfma16(qf[c], bf, accS[n]);
      }
    }
#pragma unroll
    for (int ri = 0; ri < 4; ri++) {
      int qrow = qrow_base + kg*4 + ri;
      float mx = -1e30f;
#pragma unroll
      for (int n = 0; n < 4; n++) {
        int key = ts + n*16 + arow;
        float s = (key <= qrow) ? accS[n][ri] * 0.125f : -1e30f;
        accS[n][ri] = s;
        mx = fmaxf(mx, s);
      }
      for (int off = 1; off < 16; off <<= 1) mx = fmaxf(mx, __shfl_xor(mx, off));
      float mn = fmaxf(m_[ri], mx);
      float a = __expf(m_[ri] - mn);
      float sum = 0.f;
#pragma unroll
      for (int n = 0; n < 4; n++) {
        float p = __expf(accS[n][ri] - mn);
        accS[n][ri] = p;
        sum += p;
      }
      for (int off = 1; off < 16; off <<= 1) sum += __shfl_xor(sum, off);
      l_[ri] = l_[ri] * a + sum;
      m_[ri] = mn;
#pragma unroll
      for (int n = 0; n < 4; n++) accO[n][ri] *= a;
    }
#pragma unroll
    for (int ri = 0; ri < 4; ri++)
#pragma unroll
      for (int n = 0; n < 4; n++)
        Pl[wv][kg*4 + ri][n*16 + arow] = (short)rne1(accS[n][ri]);
#pragma unroll
    for (int c = 0; c < 2; c++) {
      bf16x8 pf = *(const bf16x8*)&Pl[wv][arow][c*32 + akb];
#pragma unroll
      for (int n = 0; n < 4; n++) {
        bf16x8 vf = *(const bf16x8*)&Vt[n*16 + arow][c*32 + akb];
        accO[n] = mfma16(pf, vf, accO[n]);
      }
    }
    __syncthreads();
  }
#pragma unroll
  for (int ri = 0; ri < 4; ri++) {
    int qrow = qrow_base + kg*4 + ri;
    float inv = 1.f / l_[ri];
#pragma unroll
    for (int n = 0; n < 4; n++)
      ob[(size_t)qrow * (NHEADS*HDIM) + h * HDIM + n*16 + arow] = accO[n][ri] * inv;
  }
}

// ---------------- gate: softmax -> top-6 ----------------
__global__ __launch_bounds__(64) void gate_topk_k(const float* __restrict__ z,
    const float* __restrict__ gw, int* __restrict__ sel, float* __restrict__ topw,
    int* __restrict__ counts) {
  int t = blockIdx.x, lane = threadIdx.x;
  const float* zr = z + (size_t)t * D_MODEL;
  float acc = 0.f;
  for (int d = 0; d < D_MODEL; d += 4) {
    float4 zv = *(const float4*)(zr + d);
    acc += zv.x * gw[(size_t)(d + 0) * NEXP + lane];
    acc += zv.y * gw[(size_t)(d + 1) * NEXP + lane];
    acc += zv.z * gw[(size_t)(d + 2) * NEXP + lane];
    acc += zv.w * gw[(size_t)(d + 3) * NEXP + lane];
  }
  float m = acc;
  for (int off = 32; off; off >>= 1) m = fmaxf(m, __shfl_xor(m, off));
  float p = __expf(acc - m);
  float s = p;
  for (int off = 32; off; off >>= 1) s += __shfl_xor(s, off);
  p /= s;
  float rem = p, wsum = 0.f;
  float wvv[TOPK]; int wi[TOPK];
  for (int i = 0; i < TOPK; i++) {
    float v = rem; int idx = lane;
    for (int off = 32; off; off >>= 1) {
      float v2 = __shfl_xor(v, off);
      int i2 = __shfl_xor(idx, off);
      if (v2 > v || (v2 == v && i2 < idx)) { v = v2; idx = i2; }
    }
    wvv[i] = v; wi[i] = idx; wsum += v;
    if (lane == idx) rem = -1.f;
  }
  if (lane < TOPK) {
    sel[t * TOPK + lane] = wi[lane];
    topw[t * TOPK + lane] = wvv[lane] / wsum;
  }
  if (lane == 0)
    for (int i = 0; i < TOPK; i++) atomicAdd(&counts[wi[i]], 1);
}

// ---------------- scan + flattened (expert, mtile) work list ----------------
__global__ void scan_k(const int* __restrict__ counts, int* __restrict__ offs,
                       int* __restrict__ cursor, int* __restrict__ tile2e,
                       int* __restrict__ tile2mt, int* __restrict__ ntiles) {
  int lane = threadIdx.x;
  int c = counts[lane];
  int x = c;
  for (int off = 1; off < 64; off <<= 1) {
    int y = __shfl_up(x, off);
    if (lane >= off) x += y;
  }
  offs[lane] = x - c;
  cursor[lane] = x - c;
  int nt = (c + 127) >> 7;
  int y = nt;
  for (int off = 1; off < 64; off <<= 1) {
    int t2 = __shfl_up(y, off);
    if (lane >= off) y += t2;
  }
  int tbase = y - nt;
  for (int i = 0; i < nt; i++) { tile2e[tbase + i] = lane; tile2mt[tbase + i] = i; }
  if (lane == 63) {
    for (int i = 0; i < 8; i++) { tile2e[y + i] = NEXP; tile2mt[y + i] = i; }
    ntiles[0] = y + 8;
  }
}

__global__ void scatter_k(const int* __restrict__ sel, const float* __restrict__ topw,
    int* __restrict__ cursor, int* __restrict__ tok, float* __restrict__ wt) {
  int t = blockIdx.x * 256 + threadIdx.x;
  if (t >= SEQ) return;
  for (int i = 0; i < TOPK; i++) {
    int e = sel[t * TOPK + i];
    int pos = atomicAdd(&cursor[e], 1);
    tok[pos] = t;
    wt[pos] = topw[t * TOPK + i];
  }
}

// ---------------- weight pack: f32 [K][N] -> bf16 XOR-swizzled col-major tiles -----
// grid = (K/32, NEXP+1). tile for (e,kb,cb) = [CB cols][32 k] us, chunk-XOR on k.
__global__ __launch_bounds__(256) void pack_k(const float* __restrict__ srcE,
    const float* __restrict__ srcS, ushort* __restrict__ dst, int N, int CB) {
  __shared__ ushort L[32][1024];
  int kb = blockIdx.x, e = blockIdx.y;
  int K32 = gridDim.x;
  const float* src = (e == NEXP ? srcS : srcE + (size_t)e * K32 * 32 * N)
                     + (size_t)kb * 32 * N;
  int t = threadIdx.x;
  int nf4 = 32 * (N >> 2);
  for (int idx = t; idx < nf4; idx += 256) {
    int row = idx / (N >> 2), c4 = (idx % (N >> 2)) << 2;
    float4 v = *(const float4*)(src + (size_t)row * N + c4);
    unsigned* p = (unsigned*)&L[row][c4];
    p[0] = pk2bf(v.x, v.y); p[1] = pk2bf(v.z, v.w);
  }
  __syncthreads();
  int ncb = N / CB;
  ushort* dtile = dst + (size_t)(e * K32 + kb) * ncb * (CB * 32);
  int nout = ncb * CB * 4;
  for (int idx = t; idx < nout; idx += 256) {
    int kc = idx & 3, c = (idx >> 2) % CB, cb = idx / (4 * CB);
    int kbase = (kc ^ (c & 3)) << 3;
    union { uint4 u; ushort s[8]; } o;
#pragma unroll
    for (int j = 0; j < 8; j++) o.s[j] = L[kbase + j][cb * CB + c];
    *(uint4*)(dtile + (size_t)cb * (CB * 32) + c * 32 + kc * 8) = o.u;
  }
}

// ---------------- z gather into per-tile K-chunk layout [gt][32][128][32] ----------
__global__ __launch_bounds__(256) void zgather_k(const ushort* __restrict__ zb,
    ushort* __restrict__ zg, const int* __restrict__ tok_list,
    const int* __restrict__ counts, const int* __restrict__ offs,
    const int* __restrict__ tile2e, const int* __restrict__ tile2mt,
    const int* __restrict__ ntiles) {
  int gt = blockIdx.y;
  if (gt >= ntiles[0]) return;
  int ks = blockIdx.x;
  int e = tile2e[gt], mt = tile2mt[gt] << 7;
  bool sh = (e == NEXP);
  int cnt = sh ? SEQ : counts[e];
  int off = sh ? 0 : offs[e];
  int t = threadIdx.x;
  int row = t >> 1, half = (t & 1) << 4;
  int r = mt + row; if (r >= cnt) r = cnt - 1;
  int tok = sh ? r : tok_list[off + r];
  const uint4* s = (const uint4*)(zb + (size_t)tok * D_MODEL + ks * 32 + half);
  uint4* d = (uint4*)(zg + ((size_t)gt * 32 + ks) * 4096 + row * 32 + half);
  d[0] = s[0]; d[1] = s[1];
}

// ---------------- MoE up, packed: pure DMA, 3-buf counted vmcnt --------------------
// grid = (8, MAXTILES). NT=32.
__global__ __launch_bounds__(256) void moe_upP(const ushort* __restrict__ zg,
    const ushort* __restrict__ w1b, const ushort* __restrict__ w3b,
    ushort* __restrict__ gtl, const float* __restrict__ wt_list,
    const int* __restrict__ counts, const int* __restrict__ offs,
    const int* __restrict__ tile2e, const int* __restrict__ tile2mt,
    const int* __restrict__ ntiles) {
  int gt = blockIdx.y;
  if (gt >= ntiles[0]) return;
  int e = tile2e[gt], mt = tile2mt[gt] << 7;
  bool sh = (e == NEXP);
  int cnt = sh ? SEQ : counts[e];
  int off = sh ? 0 : offs[e];
  int cb = blockIdx.x;
  __shared__ __align__(16) ushort A_s[3][4096];
  __shared__ __align__(16) ushort B1_s[3][2048];
  __shared__ __align__(16) ushort B3_s[3][2048];
  int tid = threadIdx.x, wv = tid >> 6, lane = tid & 63;
  int arow = lane & 15, kg = lane >> 4, akb = kg << 3;
  int c0l = wv * 16 + arow;
  int c0 = (cb << 6) + c0l;
  const ushort* zt = zg + (size_t)gt * 32 * 4096;
  const ushort* w1t = w1b + ((size_t)(e * 32) * 8 + cb) * 2048;
  const ushort* w3t = w3b + ((size_t)(e * 32) * 8 + cb) * 2048;
  const int NT = 32;
  int la8 = lane * 8;
  auto STAGE = [&](int b, int s) {
    int ks = (s < NT) ? s : 0;
    const ushort* at = zt + (size_t)ks * 4096 + wv * 1024;
    gload16(at + la8,        &A_s[b][wv * 1024]);
    gload16(at + 512 + la8,  &A_s[b][wv * 1024 + 512]);
    gload16(w1t + (size_t)ks * 16384 + wv * 512 + la8, &B1_s[b][wv * 512]);
    gload16(w3t + (size_t)ks * 16384 + wv * 512 + la8, &B3_s[b][wv * 512]);
  };
  STAGE(0, 0); STAGE(1, 1); STAGE(2, 2);
  int bidx = c0l * 32 + ((kg ^ (c0l & 3)) << 3);
  f32x4 a1[8], a3[8];
#pragma unroll
  for (int f = 0; f < 8; f++) { a1[f] = (f32x4){0.f,0.f,0.f,0.f}; a3[f] = (f32x4){0.f,0.f,0.f,0.f}; }
  for (int s = 0; s < NT; ++s) {
    int b = s % 3;
    asm volatile("s_waitcnt vmcnt(8)" ::: "memory");
    __builtin_amdgcn_s_barrier();
    bf16x8 af[8];
#pragma unroll
    for (int f = 0; f < 8; f++) af[f] = *(const bf16x8*)&A_s[b][(f*16 + arow) * 32 + akb];
    bf16x8 f1 = *(const bf16x8*)&B1_s[b][bidx];
    bf16x8 f3 = *(const bf16x8*)&B3_s[b][bidx];
    asm volatile("s_waitcnt lgkmcnt(0)" ::: "memory");
    __builtin_amdgcn_s_barrier();
    STAGE(b, s + 3);
#pragma unroll
    for (int f = 0; f < 8; f++) {
      a1[f] = mfma16(af[f], f1, a1[f]);
      a3[f] = mfma16(af[f], f3, a3[f]);
    }
  }
  asm volatile("s_waitcnt vmcnt(0)" ::: "memory");
  ushort* gout = gtl + (size_t)gt * 65536 + (c0 >> 5) * 4096 + (c0 & 31);
#pragma unroll
  for (int f = 0; f < 8; f++)
#pragma unroll
    for (int ri = 0; ri < 4; ri++) {
      int lr = f*16 + kg*4 + ri;
      int r = mt + lr;
      if (r < cnt) {
        float wt = sh ? 1.0f : wt_list[off + r];
        float h1 = a1[f][ri], h3 = a3[f][ri];
        float gv = h1 / (1.f + __expf(-h1)) * h3 * wt;
        gout[lr * 32] = (ushort)rne1(gv);
      }
    }
}

// ---------------- MoE down, packed: pure DMA, 3-buf counted vmcnt ------------------
// grid = (8, MAXTILES). NT=16.
__global__ __launch_bounds__(256) void moe_downP(const ushort* __restrict__ gtl,
    const ushort* __restrict__ w2b, float* __restrict__ out,
    const int* __restrict__ tok_list, const int* __restrict__ counts,
    const int* __restrict__ offs, const int* __restrict__ tile2e,
    const int* __restrict__ tile2mt, const int* __restrict__ ntiles) {
  int gt = blockIdx.y;
  if (gt >= ntiles[0]) return;
  int e = tile2e[gt], mt = tile2mt[gt] << 7;
  bool sh = (e == NEXP);
  int cnt = sh ? SEQ : counts[e];
  int off = sh ? 0 : offs[e];
  int cb = blockIdx.x;
  __shared__ __align__(16) ushort A_s[3][4096];
  __shared__ __align__(16) ushort B_s[3][4096];
  int tid = threadIdx.x, wv = tid >> 6, lane = tid & 63;
  int arow = lane & 15, kg = lane >> 4, akb = kg << 3;
  int c0l = wv * 32 + arow;
  int c0 = (cb << 7) + c0l;
  const ushort* at0 = gtl + (size_t)gt * 65536;
  const ushort* w2t = w2b + ((size_t)(e * 16) * 8 + cb) * 4096;
  const int NT = 16;
  int la8 = lane * 8;
  auto STAGE = [&](int b, int s) {
    int ks = (s < NT) ? s : 0;
    const ushort* at = at0 + (size_t)ks * 4096 + wv * 1024;
    gload16(at + la8,       &A_s[b][wv * 1024]);
    gload16(at + 512 + la8, &A_s[b][wv * 1024 + 512]);
    const ushort* bt = w2t + (size_t)ks * 32768 + wv * 1024;
    gload16(bt + la8,       &B_s[b][wv * 1024]);
    gload16(bt + 512 + la8, &B_s[b][wv * 1024 + 512]);
  };
  STAGE(0, 0); STAGE(1, 1); STAGE(2, 2);
  int bidx0 = c0l * 32 + ((kg ^ (c0l & 3)) << 3);
  int bidx1 = (c0l + 16) * 32 + ((kg ^ (c0l & 3)) << 3);
  f32x4 ac0[8], ac1[8];
#pragma unroll
  for (int f = 0; f < 8; f++) { ac0[f] = (f32x4){0.f,0.f,0.f,0.f}; ac1[f] = (f32x4){0.f,0.f,0.f,0.f}; }
  for (int s = 0; s < NT; ++s) {
    int b = s % 3;
    asm volatile("s_waitcnt vmcnt(8)" ::: "memory");
    __builtin_amdgcn_s_barrier();
    bf16x8 af[8];
#pragma unroll
    for (int f = 0; f < 8; f++) af[f] = *(const bf16x8*)&A_s[b][(f*16 + arow) * 32 + akb];
    bf16x8 f0 = *(const bf16x8*)&B_s[b][bidx0];
    bf16x8 f1 = *(const bf16x8*)&B_s[b][bidx1];
    asm volatile("s_waitcnt lgkmcnt(0)" ::: "memory");
    __builtin_amdgcn_s_barrier();
    STAGE(b, s + 3);
#pragma unroll
    for (int f = 0; f < 8; f++) {
      ac0[f] = mfma16(af[f], f0, ac0[f]);
      ac1[f] = mfma16(af[f], f1, ac1[f]);
    }
  }
  asm volatile("s_waitcnt vmcnt(0)" ::: "memory");
#pragma unroll
  for (int f = 0; f < 8; f++)
#pragma unroll
    for (int ri = 0; ri < 4; ri++) {
      int r = mt + f*16 + kg*4 + ri;
      if (r < cnt) {
        int tok = sh ? r : tok_list[off + r];
        float* op = out + (size_t)tok * D_MODEL + c0;
        atomicAdd(op, ac0[f][ri]);
        atomicAdd(op + 16, ac1[f][ri]);
      }
    }
}

// ---------------- fallback MoE (r8): reg-staged, relaxed barrier -------------------
__global__ __launch_bounds__(256) void moe_up6(const ushort* __restrict__ zb,
    const float* __restrict__ w1, const float* __restrict__ w3, size_t wstride,
    const float* __restrict__ sw1, const float* __restrict__ sw3,
    ushort* __restrict__ g, ushort* __restrict__ sg,
    const int* __restrict__ tok_list, const float* __restrict__ wt_list,
    const int* __restrict__ counts, const int* __restrict__ offs,
    const int* __restrict__ tile2e, const int* __restrict__ tile2mt,
    const int* __restrict__ ntiles) {
  int gt = blockIdx.y;
  if (gt >= ntiles[0]) return;
  int e = tile2e[gt];
  int mt = tile2mt[gt] << 7;
  bool sh = (e == NEXP);
  int cnt = sh ? SEQ : counts[e];
  int off = sh ? 0 : offs[e];
  const float* w1p = (sh ? sw1 : w1 + (size_t)e * wstride) + (blockIdx.x << 6);
  const float* w3p = (sh ? sw3 : w3 + (size_t)e * wstride) + (blockIdx.x << 6);
  ushort* gout = sh ? sg : g;
  __shared__ ushort Ah[2][128][40];
  __shared__ ushort Bs[2][2][32][74];
  __shared__ int toks[128];
  int tid = threadIdx.x, wv = tid >> 6, lane = tid & 63;
  int arow = lane & 15, akb = (lane >> 4) << 3, kg = lane >> 4;
  int c0l = wv * 16 + arow;
  int c0 = (blockIdx.x << 6) + c0l;
  if (tid < 128) {
    int r = mt + tid; if (r >= cnt) r = cnt - 1;
    toks[tid] = sh ? r : tok_list[off + r];
  }
  __syncthreads();
  int row0 = tid >> 2, q8 = (tid & 3) << 3, row1 = row0 + 64;
  const ushort* zr0 = zb + (size_t)toks[row0] * D_MODEL + q8;
  const ushort* zr1 = zb + (size_t)toks[row1] * D_MODEL + q8;
  int kB = tid >> 4, cB = (tid & 15) << 2;
  const float* w1q = w1p + (size_t)kB * HEXP + cB;
  const float* w3q = w3p + (size_t)kB * HEXP + cB;
  uint4  ra0 = *(const uint4*)zr0;
  uint4  ra1 = *(const uint4*)zr1;
  float4 rb1a = *(const float4*)w1q;
  float4 rb1b = *(const float4*)(w1q + 16 * HEXP);
  float4 rb3a = *(const float4*)w3q;
  float4 rb3b = *(const float4*)(w3q + 16 * HEXP);
  f32x4 a1[8], a3[8];
#pragma unroll
  for (int f = 0; f < 8; f++) { a1[f] = (f32x4){0.f,0.f,0.f,0.f}; a3[f] = (f32x4){0.f,0.f,0.f,0.f}; }
  int cur = 0;
  for (int k0 = 0; k0 < D_MODEL; k0 += 32) {
    int kp = (k0 + 32 < D_MODEL) ? k0 + 32 : 0;
    uint4  na0 = *(const uint4*)(zr0 + kp);
    uint4  na1 = *(const uint4*)(zr1 + kp);
    const float* w1n = w1q + (size_t)kp * HEXP;
    const float* w3n = w3q + (size_t)kp * HEXP;
    float4 nb1a = *(const float4*)w1n;
    float4 nb1b = *(const float4*)(w1n + 16 * HEXP);
    float4 nb3a = *(const float4*)w3n;
    float4 nb3b = *(const float4*)(w3n + 16 * HEXP);
    *(uint4*)&Ah[cur][row0][q8] = ra0;
    *(uint4*)&Ah[cur][row1][q8] = ra1;
    {
      unsigned* p = (unsigned*)&Bs[cur][0][kB][cB];
      p[0] = pk2bf(rb1a.x, rb1a.y); p[1] = pk2bf(rb1a.z, rb1a.w);
      unsigned* p2 = (unsigned*)&Bs[cur][0][kB + 16][cB];
      p2[0] = pk2bf(rb1b.x, rb1b.y); p2[1] = pk2bf(rb1b.z, rb1b.w);
      unsigned* p3 = (unsigned*)&Bs[cur][1][kB][cB];
      p3[0] = pk2bf(rb3a.x, rb3a.y); p3[1] = pk2bf(rb3a.z, rb3a.w);
      unsigned* p4 = (unsigned*)&Bs[cur][1][kB + 16][cB];
      p4[0] = pk2bf(rb3b.x, rb3b.y); p4[1] = pk2bf(rb3b.z, rb3b.w);
    }
    barrier_nv();
    bf16x8 f1 = bfrag_lds<74>(&Bs[cur][0][0][0], akb, c0l);
    bf16x8 f3 = bfrag_lds<74>(&Bs[cur][1][0][0], akb, c0l);
#pragma unroll
    for (int f = 0; f < 8; f++) {
      bf16x8 ah = *(const bf16x8*)&Ah[cur][f*16 + arow][akb];
      a1[f] = mfma16(ah, f1, a1[f]);
      a3[f] = mfma16(ah, f3, a3[f]);
    }
    ra0 = na0; ra1 = na1;
    rb1a = nb1a; rb1b = nb1b; rb3a = nb3a; rb3b = nb3b;
    cur ^= 1;
  }
#pragma unroll
  for (int f = 0; f < 8; f++)
#pragma unroll
    for (int ri = 0; ri < 4; ri++) {
      int r = mt + f*16 + kg*4 + ri;
      if (r < cnt) {
        float wt = sh ? 1.0f : wt_list[off + r];
        float h1 = a1[f][ri], h3 = a3[f][ri];
        float gv = h1 / (1.f + __expf(-h1)) * h3 * wt;
        gout[(size_t)(off + r) * HEXP + c0] = (ushort)rne1(gv);
      }
    }
}

__global__ __launch_bounds__(256) void moe_down6(const ushort* __restrict__ g,
    const ushort* __restrict__ sg, const float* __restrict__ w2, size_t wstride,
    const float* __restrict__ sw2, float* __restrict__ out,
    const int* __restrict__ tok_list, const int* __restrict__ counts,
    const int* __restrict__ offs, const int* __restrict__ tile2e,
    const int* __restrict__ tile2mt, const int* __restrict__ ntiles) {
  int gt = blockIdx.y;
  if (gt >= ntiles[0]) return;
  int e = tile2e[gt];
  int mt = tile2mt[gt] << 7;
  bool sh = (e == NEXP);
  int cnt = sh ? SEQ : counts[e];
  int off = sh ? 0 : offs[e];
  const float* w2p = (sh ? sw2 : w2 + (size_t)e * wstride) + (blockIdx.x << 7);
  const ushort* gin = sh ? sg : g;
  __shared__ ushort Ah[2][128][40];
  __shared__ ushort Bs[2][32][138];
  int tid = threadIdx.x, wv = tid >> 6, lane = tid & 63;
  int arow = lane & 15, akb = (lane >> 4) << 3, kg = lane >> 4;
  int c0l = wv * 32 + arow;
  int c0 = (blockIdx.x << 7) + c0l;
  int row0 = tid >> 2, q8 = (tid & 3) << 3, row1 = row0 + 64;
  int rr0 = mt + row0; if (rr0 >= cnt) rr0 = cnt - 1;
  int rr1 = mt + row1; if (rr1 >= cnt) rr1 = cnt - 1;
  const ushort* gr0 = gin + (size_t)(off + rr0) * HEXP + q8;
  const ushort* gr1 = gin + (size_t)(off + rr1) * HEXP + q8;
  int kB = tid >> 3, cB = (tid & 7) << 4;
  const float* w2q = w2p + (size_t)kB * D_MODEL + cB;
  uint4  ra0 = *(const uint4*)gr0;
  uint4  ra1 = *(const uint4*)gr1;
  float4 rb0 = *(const float4*)(w2q);
  float4 rb1 = *(const float4*)(w2q + 4);
  float4 rb2 = *(const float4*)(w2q + 8);
  float4 rb3 = *(const float4*)(w2q + 12);
  f32x4 ac0[8], ac1[8];
#pragma unroll
  for (int f = 0; f < 8; f++) { ac0[f] = (f32x4){0.f,0.f,0.f,0.f}; ac1[f] = (f32x4){0.f,0.f,0.f,0.f}; }
  int cur = 0;
  for (int k0 = 0; k0 < HEXP; k0 += 32) {
    int kp = (k0 + 32 < HEXP) ? k0 + 32 : 0;
    uint4  na0 = *(const uint4*)(gr0 + kp);
    uint4  na1 = *(const uint4*)(gr1 + kp);
    const float* wn = w2q + (size_t)kp * D_MODEL;
    float4 nb0 = *(const float4*)(wn);
    float4 nb1 = *(const float4*)(wn + 4);
    float4 nb2 = *(const float4*)(wn + 8);
    float4 nb3 = *(const float4*)(wn + 12);
    *(uint4*)&Ah[cur][row0][q8] = ra0;
    *(uint4*)&Ah[cur][row1][q8] = ra1;
    {
      unsigned* p = (unsigned*)&Bs[cur][kB][cB];
      p[0] = pk2bf(rb0.x, rb0.y); p[1] = pk2bf(rb0.z, rb0.w);
      p[2] = pk2bf(rb1.x, rb1.y); p[3] = pk2bf(rb1.z, rb1.w);
      p[4] = pk2bf(rb2.x, rb2.y); p[5] = pk2bf(rb2.z, rb2.w);
      p[6] = pk2bf(rb3.x, rb3.y); p[7] = pk2bf(rb3.z, rb3.w);
    }
    barrier_nv();
    bf16x8 f0 = bfrag_lds<138>(&Bs[cur][0][0], akb, c0l);
    bf16x8 f1 = bfrag_lds<138>(&Bs[cur][0][0], akb, c0l + 16);
#pragma unroll
    for (int f = 0; f < 8; f++) {
      bf16x8 ah = *(const bf16x8*)&Ah[cur][f*16 + arow][akb];
      ac0[f] = mfma16(ah, f0, ac0[f]);
      ac1[f] = mfma16(ah, f1, ac1[f]);
    }
    ra0 = na0; ra1 = na1;
    rb0 = nb0; rb1 = nb1; rb2 = nb2; rb3 = nb3;
    cur ^= 1;
  }
#pragma unroll
  for (int f = 0; f < 8; f++)
#pragma unroll
    for (int ri = 0; ri < 4; ri++) {
      int r = mt + f*16 + kg*4 + ri;
      if (r < cnt) {
        int tok = sh ? r : tok_list[off + r];
        float* op = out + (size_t)tok * D_MODEL + c0;
        atomicAdd(op, ac0[f][ri]);
        atomicAdd(op + 16, ac1[f][ri]);
      }
    }
}

// ---------------- host ----------------
extern "C" void kernel_launch(void* const* d_in, const int* in_sizes, int n_in,
                              void* d_out, int out_size, void* d_ws, size_t ws_size,
                              hipStream_t stream) {
  const float* x     = (const float*)d_in[0];
  const float* fcos  = (const float*)d_in[1];
  const float* fsin  = (const float*)d_in[2];
  const float* anw   = (const float*)d_in[3];
  const float* fnw   = (const float*)d_in[4];
  const float* wq    = (const float*)d_in[5];
  const float* wk    = (const float*)d_in[6];
  const float* wvv   = (const float*)d_in[7];
  const float* wo    = (const float*)d_in[8];
  const float* qnw   = (const float*)d_in[9];
  const float* knw   = (const float*)d_in[10];
  const float* gatew = (const float*)d_in[11];
  const float* w1e   = (const float*)d_in[12];
  const float* w3e   = (const float*)d_in[13];
  const float* w2e   = (const float*)d_in[14];
  const float* sw1   = (const float*)d_in[15];
  const float* sw3   = (const float*)d_in[16];
  const float* sw2   = (const float*)d_in[17];
  float* out = (float*)d_out;

  char* ws = (char*)d_ws;
  const size_t MB = 1ull << 20;
  float*  hx    = (float*)(ws);             // 0-4
  float*  h     = (float*)(ws + 4*MB);      // 4-8
  float*  z     = (float*)(ws + 8*MB);      // 8-12
  float*  qbuf  = (float*)(ws + 12*MB);     // 12-16 (dead after attn)
  float*  kbuf  = (float*)(ws + 16*MB);     // 16-17
  float*  vbuf  = (float*)(ws + 17*MB);     // 17-18
  ushort* zb    = (ushort*)(ws + 12*MB);    // 12-14 bf16 z (overlaps dead qbuf)
  char*   misc  = ws + 22*MB;
  int*   sel      = (int*)(misc);
  float* topw     = (float*)(misc + 24576);
  int*   counts   = (int*)(misc + 49152);
  int*   offs     = (int*)(misc + 49408);
  int*   cursor   = (int*)(misc + 49664);
  int*   ntiles   = (int*)(misc + 50432);
  int*   tile2e   = (int*)(misc + 50688);
  int*   tile2mt  = (int*)(misc + 51200);
  int*   tok_list = (int*)(misc + 51712);
  float* wt_list  = (float*)(misc + 76288);
  // packed-path buffers
  ushort* zg   = (ushort*)(ws + 24*MB);     // 24-56  (31.5 MB)
  ushort* gtl  = (ushort*)(ws + 56*MB);     // 56-72  (15.7 MB)
  ushort* w1b  = (ushort*)(ws + 72*MB);     // 72-141 (68.2 MB)
  ushort* w3b  = (ushort*)(ws + 141*MB);    // 141-210
  ushort* w2b  = (ushort*)(ws + 210*MB);    // 210-279
  bool packed = ws_size >= 280*MB;
  // fallback-path buffers (fit under 22 MB)
  ushort* gbF   = (ushort*)(ws + 14*MB);
  ushort* s_gbF = (ushort*)(ws + 20*MB + 512*1024);

  rmsnorm_k<<<SEQ, 256, 0, stream>>>(x, anw, hx, nullptr);
  mfma_gemm_k<<<dim3(8, 64), 256, 0, stream>>>(hx, wq, qbuf, nullptr, nullptr, 1024, 1024);
  mfma_gemm_k<<<dim3(2, 64), 256, 0, stream>>>(hx, wk, kbuf, nullptr, nullptr, 256, 1024);
  mfma_gemm_k<<<dim3(2, 64), 256, 0, stream>>>(hx, wvv, vbuf, nullptr, nullptr, 256, 1024);
  qknorm_rope_k<<<dim3(SEQ, NHEADS + NKVH), 64, 0, stream>>>(qbuf, kbuf, qnw, knw, fcos, fsin);
  attn_mfma<<<dim3(SEQ / 64, NHEADS), 256, 0, stream>>>(qbuf, kbuf, vbuf, hx);
  mfma_gemm_k<<<dim3(8, 64), 256, 0, stream>>>(hx, wo, h, out, x, 1024, 1024);
  rmsnorm_k<<<SEQ, 256, 0, stream>>>(h, fnw, z, zb);
  hipMemsetAsync(counts, 0, 256, stream);
  gate_topk_k<<<SEQ, 64, 0, stream>>>(z, gatew, sel, topw, counts);
  scan_k<<<1, 64, 0, stream>>>(counts, offs, cursor, tile2e, tile2mt, ntiles);
  scatter_k<<<SEQ / 256, 256, 0, stream>>>(sel, topw, cursor, tok_list, wt_list);

  if (packed) {
    pack_k<<<dim3(16, NEXP + 1), 256, 0, stream>>>(w2e, sw2, w2b, 1024, 128);
    pack_k<<<dim3(32, NEXP + 1), 256, 0, stream>>>(w1e, sw1, w1b, 512, 64);
    pack_k<<<dim3(32, NEXP + 1), 256, 0, stream>>>(w3e, sw3, w3b, 512, 64);
    zgather_k<<<dim3(32, MAXTILES), 256, 0, stream>>>(zb, zg, tok_list,
        counts, offs, tile2e, tile2mt, ntiles);
    moe_upP<<<dim3(8, MAXTILES), 256, 0, stream>>>(zg, w1b, w3b, gtl, wt_list,
        counts, offs, tile2e, tile2mt, ntiles);
    moe_downP<<<dim3(8, MAXTILES), 256, 0, stream>>>(gtl, w2b, out, tok_list,
        counts, offs, tile2e, tile2mt, ntiles);
  } else {
    moe_up6<<<dim3(HEXP / 64, MAXTILES), 256, 0, stream>>>(zb, w1e, w3e,
        (size_t)D_MODEL * HEXP, sw1, sw3, gbF, s_gbF, tok_list, wt_list,
        counts, offs, tile2e, tile2mt, ntiles);
    moe_down6<<<dim3(D_MODEL / 128, MAXTILES), 256, 0, stream>>>(gbF, s_gbF, w2e,
        (size_t)HEXP * D_MODEL, sw2, out, tok_list, counts, offs,
        tile2e, tile2mt, ntiles);
  }
  (void)in_sizes; (void)n_in; (void)out_size; (void)ws_size;
}

// Round 13
// 419.459 us; speedup vs baseline: 1.3162x; 1.3162x over previous
//
#include <hip/hip_runtime.h>
#include <hip/hip_bf16.h>
#include <math.h>

#define D_MODEL 1024
#define SEQ     1024
#define NHEADS  16
#define NKVH    4
#define HDIM    64
#define NEXP    64
#define TOPK    6
#define HEXP    512
#define EPS     1e-5f
#define MAXTILES 120   // 112 expert tiles max + 8 shared-expert tiles

typedef __attribute__((ext_vector_type(8))) short bf16x8;
typedef __attribute__((ext_vector_type(4))) float f32x4;

struct bfrag2 { bf16x8 hi, lo; };
struct f32x8r { float v[8]; };

__device__ __forceinline__ unsigned rne1(float a) {
  union { float f; unsigned u; } x; x.f = a;
  return (x.u + 0x7fffu + ((x.u >> 16) & 1u)) >> 16;
}
__device__ __forceinline__ float frombf(unsigned h) {
  union { float f; unsigned u; } x; x.u = h << 16; return x.f;
}
__device__ __forceinline__ void split_pack(float a, float b, unsigned& hi, unsigned& lo) {
  unsigned ha = rne1(a), hb = rne1(b);
  hi = ha | (hb << 16);
  lo = rne1(a - frombf(ha)) | (rne1(b - frombf(hb)) << 16);
}
__device__ __forceinline__ unsigned pk2bf(float a, float b) {
  return rne1(a) | (rne1(b) << 16);
}

__device__ __forceinline__ f32x4 mfma16(bf16x8 a, bf16x8 b, f32x4 c) {
  return __builtin_amdgcn_mfma_f32_16x16x32_bf16(a, b, c, 0, 0, 0);
}
__device__ __forceinline__ f32x4 mfma_sp(bf16x8 ah, bf16x8 al, const bfrag2& b, f32x4 c) {
  c = mfma16(ah, b.hi, c);
  c = mfma16(ah, b.lo, c);
  c = mfma16(al, b.hi, c);
  return c;
}

// barrier WITHOUT the compiler's vmcnt(0) drain: LDS ordered, global loads in flight
__device__ __forceinline__ void barrier_nv() {
  asm volatile("s_waitcnt lgkmcnt(0)" ::: "memory");
  __builtin_amdgcn_s_barrier();
}

__device__ __forceinline__ f32x8r loadraw8(const float* __restrict__ p, int ld) {
  f32x8r r;
#pragma unroll
  for (int i = 0; i < 8; i++) r.v[i] = p[(size_t)ld * i];
  return r;
}
__device__ __forceinline__ bfrag2 cvt_bf2(const f32x8r& f) {
  union { bf16x8 v; unsigned u[4]; } H, L;
  split_pack(f.v[0], f.v[1], H.u[0], L.u[0]);
  split_pack(f.v[2], f.v[3], H.u[1], L.u[1]);
  split_pack(f.v[4], f.v[5], H.u[2], L.u[2]);
  split_pack(f.v[6], f.v[7], H.u[3], L.u[3]);
  bfrag2 r; r.hi = H.v; r.lo = L.v; return r;
}
template<int RL>
__device__ __forceinline__ bf16x8 bfrag_lds(const ushort* __restrict__ B, int akb, int c) {
  union { bf16x8 v; ushort s[8]; } r;
#pragma unroll
  for (int j = 0; j < 8; j++) r.s[j] = B[(akb + j) * RL + c];
  return r.v;
}

// ---------------- rmsnorm over D=1024 (+ optional bf16 copy) ----------------
__global__ __launch_bounds__(256) void rmsnorm_k(const float* __restrict__ x,
    const float* __restrict__ w, float* __restrict__ out, ushort* __restrict__ outb) {
  int t = blockIdx.x;
  const float4* xr = (const float4*)(x + (size_t)t * D_MODEL);
  float4 v = xr[threadIdx.x];
  float ss = v.x*v.x + v.y*v.y + v.z*v.z + v.w*v.w;
  for (int off = 32; off; off >>= 1) ss += __shfl_xor(ss, off);
  __shared__ float red[4];
  if ((threadIdx.x & 63) == 0) red[threadIdx.x >> 6] = ss;
  __syncthreads();
  float tot = red[0] + red[1] + red[2] + red[3];
  float inv = rsqrtf(tot * (1.f / D_MODEL) + EPS);
  float4 wv = ((const float4*)w)[threadIdx.x];
  float4 o;
  o.x = v.x * inv * wv.x; o.y = v.y * inv * wv.y;
  o.z = v.z * inv * wv.z; o.w = v.w * inv * wv.w;
  ((float4*)(out + (size_t)t * D_MODEL))[threadIdx.x] = o;
  if (outb) {
    uint2 b;
    b.x = pk2bf(o.x, o.y); b.y = pk2bf(o.z, o.w);
    *(uint2*)(outb + (size_t)t * D_MODEL + threadIdx.x * 4) = b;
  }
}

// ---------------- dense split-bf16 MFMA GEMM, depth-2, relaxed barrier ----------
__global__ __launch_bounds__(256) void mfma_gemm_k(const float* __restrict__ A,
    const float* __restrict__ B, float* __restrict__ C, float* __restrict__ C2,
    const float* __restrict__ resid, int N, int K) {
  __shared__ short Ah[2][16][40];
  __shared__ short Al[2][16][40];
  int bm = blockIdx.y << 4, bn = blockIdx.x << 7;
  int tid = threadIdx.x, wv = tid >> 6, lane = tid & 63;
  int m_ = tid >> 4, k_ = (tid & 15) << 1;
  int arow = lane & 15, akb = (lane >> 4) << 3;
  int c0 = bn + wv * 32 + arow;
  const float* ar = A + (size_t)(bm + m_) * K + k_;
  {
    float2 a0 = *(const float2*)ar;
    unsigned hi, lo; split_pack(a0.x, a0.y, hi, lo);
    *(unsigned*)&Ah[0][m_][k_] = hi;
    *(unsigned*)&Al[0][m_][k_] = lo;
  }
  float2 aO = *(const float2*)(ar + 32);
  float2 aE;
  f32x8r bE0 = loadraw8(B + (size_t)akb * N + c0, N);
  f32x8r bE1 = loadraw8(B + (size_t)akb * N + c0 + 16, N);
  f32x8r bO0 = loadraw8(B + (size_t)(32 + akb) * N + c0, N);
  f32x8r bO1 = loadraw8(B + (size_t)(32 + akb) * N + c0 + 16, N);
  __syncthreads();
  f32x4 acc0 = {0.f,0.f,0.f,0.f}, acc1 = {0.f,0.f,0.f,0.f};
  for (int k0 = 0; k0 < K; k0 += 64) {
    {
      int kp = (k0 + 64 < K) ? k0 + 64 : 0;
      f32x8r n0 = loadraw8(B + (size_t)(kp + akb) * N + c0, N);
      f32x8r n1 = loadraw8(B + (size_t)(kp + akb) * N + c0 + 16, N);
      float2 an = *(const float2*)(ar + kp);
      bfrag2 f0 = cvt_bf2(bE0), f1 = cvt_bf2(bE1);
      bf16x8 ah = *(const bf16x8*)&Ah[0][arow][akb];
      bf16x8 al = *(const bf16x8*)&Al[0][arow][akb];
      acc0 = mfma_sp(ah, al, f0, acc0);
      acc1 = mfma_sp(ah, al, f1, acc1);
      unsigned hi, lo; split_pack(aO.x, aO.y, hi, lo);
      *(unsigned*)&Ah[1][m_][k_] = hi;
      *(unsigned*)&Al[1][m_][k_] = lo;
      barrier_nv();
      bE0 = n0; bE1 = n1; aE = an;
    }
    {
      int kp = (k0 + 96 < K) ? k0 + 96 : 0;
      f32x8r n0 = loadraw8(B + (size_t)(kp + akb) * N + c0, N);
      f32x8r n1 = loadraw8(B + (size_t)(kp + akb) * N + c0 + 16, N);
      float2 an = *(const float2*)(ar + kp);
      bfrag2 f0 = cvt_bf2(bO0), f1 = cvt_bf2(bO1);
      bf16x8 ah = *(const bf16x8*)&Ah[1][arow][akb];
      bf16x8 al = *(const bf16x8*)&Al[1][arow][akb];
      acc0 = mfma_sp(ah, al, f0, acc0);
      acc1 = mfma_sp(ah, al, f1, acc1);
      unsigned hi, lo; split_pack(aE.x, aE.y, hi, lo);
      *(unsigned*)&Ah[0][m_][k_] = hi;
      *(unsigned*)&Al[0][m_][k_] = lo;
      barrier_nv();
      bO0 = n0; bO1 = n1; aO = an;
    }
  }
  int r0 = (lane >> 4) << 2;
#pragma unroll
  for (int ri = 0; ri < 4; ri++) {
    int row = bm + r0 + ri;
    size_t o0 = (size_t)row * N + c0;
    float v0 = acc0[ri], v1 = acc1[ri];
    if (resid) { v0 += resid[o0]; v1 += resid[o0 + 16]; }
    C[o0] = v0; C[o0 + 16] = v1;
    if (C2) { C2[o0] = v0; C2[o0 + 16] = v1; }
  }
}

// ---------------- per-head rmsnorm + RoPE ----------------
__global__ __launch_bounds__(64) void qknorm_rope_k(float* __restrict__ qb,
    float* __restrict__ kb, const float* __restrict__ qw, const float* __restrict__ kw,
    const float* __restrict__ fcos, const float* __restrict__ fsin) {
  int t = blockIdx.x, hid = blockIdx.y, lane = threadIdx.x;
  float* p; const float* w;
  if (hid < NHEADS) { p = qb + (size_t)t * (NHEADS*HDIM) + hid * HDIM; w = qw; }
  else              { p = kb + (size_t)t * (NKVH*HDIM) + (hid - NHEADS) * HDIM; w = kw; }
  float v = p[lane];
  float ss = v * v;
  for (int off = 32; off; off >>= 1) ss += __shfl_xor(ss, off);
  float vn = v * rsqrtf(ss * (1.f / HDIM) + EPS) * w[lane];
  int pi = lane >> 1;
  float c = fcos[t * (HDIM/2) + pi], s = fsin[t * (HDIM/2) + pi];
  float other = __shfl_xor(vn, 1);
  float o = (lane & 1) ? (other * s + vn * c) : (vn * c - other * s);
  p[lane] = o;
}

// ---------------- causal flash attention v2: 32-row/2-wave blocks ----------------
// grid = (SEQ/32, NHEADS), 128 thr. Reversed qtile order (heavy blocks first).
__global__ __launch_bounds__(128) void attn_mfma2(const float* __restrict__ qb,
    const float* __restrict__ kb, const float* __restrict__ vb, float* __restrict__ ob) {
  int h = blockIdx.y;
  int qt = (SEQ / 32 - 1) - blockIdx.x;
  int qbase = qt << 5;
  int kvh = h >> 2;
  int tid = threadIdx.x, wv = tid >> 6, lane = tid & 63;
  __shared__ short Kt[64][72];      // [key][d]
  __shared__ short Vt[64][72];      // [d][key]
  __shared__ short Pl[2][16][72];
  int arow = lane & 15;
  int akb = (lane >> 4) << 3;
  int kg = lane >> 4;
  int qrow_base = qbase + wv * 16;
  bf16x8 qf[2];
  {
    const float* qp = qb + (size_t)(qrow_base + arow) * (NHEADS*HDIM) + h * HDIM;
#pragma unroll
    for (int c = 0; c < 2; c++) {
      int d0 = akb + c * 32;
      union { bf16x8 v; unsigned u[4]; } r;
#pragma unroll
      for (int j = 0; j < 4; j++) r.u[j] = pk2bf(qp[d0 + 2*j], qp[d0 + 2*j + 1]);
      qf[c] = r.v;
    }
  }
  f32x4 accO[4];
  float m_[4], l_[4];
#pragma unroll
  for (int n = 0; n < 4; n++) { accO[n] = (f32x4){0.f,0.f,0.f,0.f}; m_[n] = -1e30f; l_[n] = 0.f; }
  int ntiles = (qbase >> 6) + 1;
  for (int ti = 0; ti < ntiles; ti++) {
    int ts = ti << 6;
    // stage K (row-major) and V (transposed) via float4 loads
#pragma unroll
    for (int i = 0; i < 8; i++) {
      int f = tid + i * 128;           // f4-unit index in [0,1024)
      int kk = f >> 4, d4 = (f & 15) << 2;
      size_t src = (size_t)(ts + kk) * (NKVH*HDIM) + kvh * HDIM + d4;
      float4 k4 = *(const float4*)(kb + src);
      float4 v4 = *(const float4*)(vb + src);
      ushort kp0 = rne1(k4.x), kp1 = rne1(k4.y), kp2 = rne1(k4.z), kp3 = rne1(k4.w);
      unsigned* kd = (unsigned*)&Kt[kk][d4];
      kd[0] = (unsigned)kp0 | ((unsigned)kp1 << 16);
      kd[1] = (unsigned)kp2 | ((unsigned)kp3 << 16);
      Vt[d4 + 0][kk] = (short)rne1(v4.x);
      Vt[d4 + 1][kk] = (short)rne1(v4.y);
      Vt[d4 + 2][kk] = (short)rne1(v4.z);
      Vt[d4 + 3][kk] = (short)rne1(v4.w);
    }
    __syncthreads();
    f32x4 accS[4];
#pragma unroll
    for (int n = 0; n < 4; n++) accS[n] = (f32x4){0.f,0.f,0.f,0.f};
#pragma unroll
    for (int c = 0; c < 2; c++) {
#pragma unroll
      for (int n = 0; n < 4; n++) {
        bf16x8 bf = *(const bf16x8*)&Kt[n*16 + arow][c*32 + akb];
        accS[n] = mfma16(qf[c], bf, accS[n]);
      }
    }
#pragma unroll
    for (int ri = 0; ri < 4; ri++) {
      int qrow = qrow_base + kg*4 + ri;
      float mx = -1e30f;
#pragma unroll
      for (int n = 0; n < 4; n++) {
        int key = ts + n*16 + arow;
        float s = (key <= qrow) ? accS[n][ri] * 0.125f : -1e30f;
        accS[n][ri] = s;
        mx = fmaxf(mx, s);
      }
      for (int off = 1; off < 16; off <<= 1) mx = fmaxf(mx, __shfl_xor(mx, off));
      float mn = fmaxf(m_[ri], mx);
      float a = __expf(m_[ri] - mn);
      float sum = 0.f;
#pragma unroll
      for (int n = 0; n < 4; n++) {
        float p = __expf(accS[n][ri] - mn);
        accS[n][ri] = p;
        sum += p;
      }
      for (int off = 1; off < 16; off <<= 1) sum += __shfl_xor(sum, off);
      l_[ri] = l_[ri] * a + sum;
      m_[ri] = mn;
#pragma unroll
      for (int n = 0; n < 4; n++) accO[n][ri] *= a;
    }
#pragma unroll
    for (int ri = 0; ri < 4; ri++)
#pragma unroll
      for (int n = 0; n < 4; n++)
        Pl[wv][kg*4 + ri][n*16 + arow] = (short)rne1(accS[n][ri]);
#pragma unroll
    for (int c = 0; c < 2; c++) {
      bf16x8 pf = *(const bf16x8*)&Pl[wv][arow][c*32 + akb];
#pragma unroll
      for (int n = 0; n < 4; n++) {
        bf16x8 vf = *(const bf16x8*)&Vt[n*16 + arow][c*32 + akb];
        accO[n] = mfma16(pf, vf, accO[n]);
      }
    }
    __syncthreads();
  }
#pragma unroll
  for (int ri = 0; ri < 4; ri++) {
    int qrow = qrow_base + kg*4 + ri;
    float inv = 1.f / l_[ri];
#pragma unroll
    for (int n = 0; n < 4; n++)
      ob[(size_t)qrow * (NHEADS*HDIM) + h * HDIM + n*16 + arow] = accO[n][ri] * inv;
  }
}

// ---------------- gate: softmax -> top-6 (low-index tie-break) ----------------
__global__ __launch_bounds__(64) void gate_topk_k(const float* __restrict__ z,
    const float* __restrict__ gw, int* __restrict__ sel, float* __restrict__ topw,
    int* __restrict__ counts) {
  int t = blockIdx.x, lane = threadIdx.x;
  const float* zr = z + (size_t)t * D_MODEL;
  float acc = 0.f;
  for (int d = 0; d < D_MODEL; d += 4) {
    float4 zv = *(const float4*)(zr + d);
    acc += zv.x * gw[(size_t)(d + 0) * NEXP + lane];
    acc += zv.y * gw[(size_t)(d + 1) * NEXP + lane];
    acc += zv.z * gw[(size_t)(d + 2) * NEXP + lane];
    acc += zv.w * gw[(size_t)(d + 3) * NEXP + lane];
  }
  float m = acc;
  for (int off = 32; off; off >>= 1) m = fmaxf(m, __shfl_xor(m, off));
  float p = __expf(acc - m);
  float s = p;
  for (int off = 32; off; off >>= 1) s += __shfl_xor(s, off);
  p /= s;
  float rem = p, wsum = 0.f;
  float wvv[TOPK]; int wi[TOPK];
  for (int i = 0; i < TOPK; i++) {
    float v = rem; int idx = lane;
    for (int off = 32; off; off >>= 1) {
      float v2 = __shfl_xor(v, off);
      int i2 = __shfl_xor(idx, off);
      if (v2 > v || (v2 == v && i2 < idx)) { v = v2; idx = i2; }
    }
    wvv[i] = v; wi[i] = idx; wsum += v;
    if (lane == idx) rem = -1.f;
  }
  if (lane < TOPK) {
    sel[t * TOPK + lane] = wi[lane];
    topw[t * TOPK + lane] = wvv[lane] / wsum;
  }
  if (lane == 0)
    for (int i = 0; i < TOPK; i++) atomicAdd(&counts[wi[i]], 1);
}

// ---------------- scan + flattened (expert, mtile) work list (+shared tiles) -------
__global__ void scan_k(const int* __restrict__ counts, int* __restrict__ offs,
                       int* __restrict__ cursor, int* __restrict__ tile2e,
                       int* __restrict__ tile2mt, int* __restrict__ ntiles) {
  int lane = threadIdx.x;
  int c = counts[lane];
  int x = c;
  for (int off = 1; off < 64; off <<= 1) {
    int y = __shfl_up(x, off);
    if (lane >= off) x += y;
  }
  offs[lane] = x - c;
  cursor[lane] = x - c;
  int nt = (c + 127) >> 7;
  int y = nt;
  for (int off = 1; off < 64; off <<= 1) {
    int t2 = __shfl_up(y, off);
    if (lane >= off) y += t2;
  }
  int tbase = y - nt;
  for (int i = 0; i < nt; i++) { tile2e[tbase + i] = lane; tile2mt[tbase + i] = i; }
  if (lane == 63) {
    for (int i = 0; i < 8; i++) { tile2e[y + i] = NEXP; tile2mt[y + i] = i; }
    ntiles[0] = y + 8;
  }
}

__global__ void scatter_k(const int* __restrict__ sel, const float* __restrict__ topw,
    int* __restrict__ cursor, int* __restrict__ tok, float* __restrict__ wt) {
  int t = blockIdx.x * 256 + threadIdx.x;
  if (t >= SEQ) return;
  for (int i = 0; i < TOPK; i++) {
    int e = sel[t * TOPK + i];
    int pos = atomicAdd(&cursor[e], 1);
    tok[pos] = t;
    wt[pos] = topw[t * TOPK + i];
  }
}

// ---------------- MoE phase A (r8): coalesced-LDS B, relaxed barrier, dbuf ---------
__global__ __launch_bounds__(256) void moe_up6(const ushort* __restrict__ zb,
    const float* __restrict__ w1, const float* __restrict__ w3, size_t wstride,
    const float* __restrict__ sw1, const float* __restrict__ sw3,
    ushort* __restrict__ g, ushort* __restrict__ sg,
    const int* __restrict__ tok_list, const float* __restrict__ wt_list,
    const int* __restrict__ counts, const int* __restrict__ offs,
    const int* __restrict__ tile2e, const int* __restrict__ tile2mt,
    const int* __restrict__ ntiles) {
  int gt = blockIdx.y;
  if (gt >= ntiles[0]) return;
  int e = tile2e[gt];
  int mt = tile2mt[gt] << 7;
  bool sh = (e == NEXP);
  int cnt = sh ? SEQ : counts[e];
  int off = sh ? 0 : offs[e];
  const float* w1p = (sh ? sw1 : w1 + (size_t)e * wstride) + (blockIdx.x << 6);
  const float* w3p = (sh ? sw3 : w3 + (size_t)e * wstride) + (blockIdx.x << 6);
  ushort* gout = sh ? sg : g;
  __shared__ ushort Ah[2][128][40];
  __shared__ ushort Bs[2][2][32][74];
  __shared__ int toks[128];
  int tid = threadIdx.x, wv = tid >> 6, lane = tid & 63;
  int arow = lane & 15, akb = (lane >> 4) << 3, kg = lane >> 4;
  int c0l = wv * 16 + arow;
  int c0 = (blockIdx.x << 6) + c0l;
  if (tid < 128) {
    int r = mt + tid; if (r >= cnt) r = cnt - 1;
    toks[tid] = sh ? r : tok_list[off + r];
  }
  __syncthreads();
  int row0 = tid >> 2, q8 = (tid & 3) << 3, row1 = row0 + 64;
  const ushort* zr0 = zb + (size_t)toks[row0] * D_MODEL + q8;
  const ushort* zr1 = zb + (size_t)toks[row1] * D_MODEL + q8;
  int kB = tid >> 4, cB = (tid & 15) << 2;
  const float* w1q = w1p + (size_t)kB * HEXP + cB;
  const float* w3q = w3p + (size_t)kB * HEXP + cB;
  uint4  ra0 = *(const uint4*)zr0;
  uint4  ra1 = *(const uint4*)zr1;
  float4 rb1a = *(const float4*)w1q;
  float4 rb1b = *(const float4*)(w1q + 16 * HEXP);
  float4 rb3a = *(const float4*)w3q;
  float4 rb3b = *(const float4*)(w3q + 16 * HEXP);
  f32x4 a1[8], a3[8];
#pragma unroll
  for (int f = 0; f < 8; f++) { a1[f] = (f32x4){0.f,0.f,0.f,0.f}; a3[f] = (f32x4){0.f,0.f,0.f,0.f}; }
  int cur = 0;
  for (int k0 = 0; k0 < D_MODEL; k0 += 32) {
    int kp = (k0 + 32 < D_MODEL) ? k0 + 32 : 0;
    uint4  na0 = *(const uint4*)(zr0 + kp);
    uint4  na1 = *(const uint4*)(zr1 + kp);
    const float* w1n = w1q + (size_t)kp * HEXP;
    const float* w3n = w3q + (size_t)kp * HEXP;
    float4 nb1a = *(const float4*)w1n;
    float4 nb1b = *(const float4*)(w1n + 16 * HEXP);
    float4 nb3a = *(const float4*)w3n;
    float4 nb3b = *(const float4*)(w3n + 16 * HEXP);
    *(uint4*)&Ah[cur][row0][q8] = ra0;
    *(uint4*)&Ah[cur][row1][q8] = ra1;
    {
      unsigned* p = (unsigned*)&Bs[cur][0][kB][cB];
      p[0] = pk2bf(rb1a.x, rb1a.y); p[1] = pk2bf(rb1a.z, rb1a.w);
      unsigned* p2 = (unsigned*)&Bs[cur][0][kB + 16][cB];
      p2[0] = pk2bf(rb1b.x, rb1b.y); p2[1] = pk2bf(rb1b.z, rb1b.w);
      unsigned* p3 = (unsigned*)&Bs[cur][1][kB][cB];
      p3[0] = pk2bf(rb3a.x, rb3a.y); p3[1] = pk2bf(rb3a.z, rb3a.w);
      unsigned* p4 = (unsigned*)&Bs[cur][1][kB + 16][cB];
      p4[0] = pk2bf(rb3b.x, rb3b.y); p4[1] = pk2bf(rb3b.z, rb3b.w);
    }
    barrier_nv();
    bf16x8 f1 = bfrag_lds<74>(&Bs[cur][0][0][0], akb, c0l);
    bf16x8 f3 = bfrag_lds<74>(&Bs[cur][1][0][0], akb, c0l);
#pragma unroll
    for (int f = 0; f < 8; f++) {
      bf16x8 ah = *(const bf16x8*)&Ah[cur][f*16 + arow][akb];
      a1[f] = mfma16(ah, f1, a1[f]);
      a3[f] = mfma16(ah, f3, a3[f]);
    }
    ra0 = na0; ra1 = na1;
    rb1a = nb1a; rb1b = nb1b; rb3a = nb3a; rb3b = nb3b;
    cur ^= 1;
  }
#pragma unroll
  for (int f = 0; f < 8; f++)
#pragma unroll
    for (int ri = 0; ri < 4; ri++) {
      int r = mt + f*16 + kg*4 + ri;
      if (r < cnt) {
        float wt = sh ? 1.0f : wt_list[off + r];
        float h1 = a1[f][ri], h3 = a3[f][ri];
        float gv = h1 / (1.f + __expf(-h1)) * h3 * wt;
        gout[(size_t)(off + r) * HEXP + c0] = (ushort)rne1(gv);
      }
    }
}

// ---------------- MoE phase B (r8): coalesced-LDS B, relaxed barrier, dbuf ---------
__global__ __launch_bounds__(256) void moe_down6(const ushort* __restrict__ g,
    const ushort* __restrict__ sg, const float* __restrict__ w2, size_t wstride,
    const float* __restrict__ sw2, float* __restrict__ out,
    const int* __restrict__ tok_list, const int* __restrict__ counts,
    const int* __restrict__ offs, const int* __restrict__ tile2e,
    const int* __restrict__ tile2mt, const int* __restrict__ ntiles) {
  int gt = blockIdx.y;
  if (gt >= ntiles[0]) return;
  int e = tile2e[gt];
  int mt = tile2mt[gt] << 7;
  bool sh = (e == NEXP);
  int cnt = sh ? SEQ : counts[e];
  int off = sh ? 0 : offs[e];
  const float* w2p = (sh ? sw2 : w2 + (size_t)e * wstride) + (blockIdx.x << 7);
  const ushort* gin = sh ? sg : g;
  __shared__ ushort Ah[2][128][40];
  __shared__ ushort Bs[2][32][138];
  int tid = threadIdx.x, wv = tid >> 6, lane = tid & 63;
  int arow = lane & 15, akb = (lane >> 4) << 3, kg = lane >> 4;
  int c0l = wv * 32 + arow;
  int c0 = (blockIdx.x << 7) + c0l;
  int row0 = tid >> 2, q8 = (tid & 3) << 3, row1 = row0 + 64;
  int rr0 = mt + row0; if (rr0 >= cnt) rr0 = cnt - 1;
  int rr1 = mt + row1; if (rr1 >= cnt) rr1 = cnt - 1;
  const ushort* gr0 = gin + (size_t)(off + rr0) * HEXP + q8;
  const ushort* gr1 = gin + (size_t)(off + rr1) * HEXP + q8;
  int kB = tid >> 3, cB = (tid & 7) << 4;
  const float* w2q = w2p + (size_t)kB * D_MODEL + cB;
  uint4  ra0 = *(const uint4*)gr0;
  uint4  ra1 = *(const uint4*)gr1;
  float4 rb0 = *(const float4*)(w2q);
  float4 rb1 = *(const float4*)(w2q + 4);
  float4 rb2 = *(const float4*)(w2q + 8);
  float4 rb3 = *(const float4*)(w2q + 12);
  f32x4 ac0[8], ac1[8];
#pragma unroll
  for (int f = 0; f < 8; f++) { ac0[f] = (f32x4){0.f,0.f,0.f,0.f}; ac1[f] = (f32x4){0.f,0.f,0.f,0.f}; }
  int cur = 0;
  for (int k0 = 0; k0 < HEXP; k0 += 32) {
    int kp = (k0 + 32 < HEXP) ? k0 + 32 : 0;
    uint4  na0 = *(const uint4*)(gr0 + kp);
    uint4  na1 = *(const uint4*)(gr1 + kp);
    const float* wn = w2q + (size_t)kp * D_MODEL;
    float4 nb0 = *(const float4*)(wn);
    float4 nb1 = *(const float4*)(wn + 4);
    float4 nb2 = *(const float4*)(wn + 8);
    float4 nb3 = *(const float4*)(wn + 12);
    *(uint4*)&Ah[cur][row0][q8] = ra0;
    *(uint4*)&Ah[cur][row1][q8] = ra1;
    {
      unsigned* p = (unsigned*)&Bs[cur][kB][cB];
      p[0] = pk2bf(rb0.x, rb0.y); p[1] = pk2bf(rb0.z, rb0.w);
      p[2] = pk2bf(rb1.x, rb1.y); p[3] = pk2bf(rb1.z, rb1.w);
      p[4] = pk2bf(rb2.x, rb2.y); p[5] = pk2bf(rb2.z, rb2.w);
      p[6] = pk2bf(rb3.x, rb3.y); p[7] = pk2bf(rb3.z, rb3.w);
    }
    barrier_nv();
    bf16x8 f0 = bfrag_lds<138>(&Bs[cur][0][0], akb, c0l);
    bf16x8 f1 = bfrag_lds<138>(&Bs[cur][0][0], akb, c0l + 16);
#pragma unroll
    for (int f = 0; f < 8; f++) {
      bf16x8 ah = *(const bf16x8*)&Ah[cur][f*16 + arow][akb];
      ac0[f] = mfma16(ah, f0, ac0[f]);
      ac1[f] = mfma16(ah, f1, ac1[f]);
    }
    ra0 = na0; ra1 = na1;
    rb0 = nb0; rb1 = nb1; rb2 = nb2; rb3 = nb3;
    cur ^= 1;
  }
#pragma unroll
  for (int f = 0; f < 8; f++)
#pragma unroll
    for (int ri = 0; ri < 4; ri++) {
      int r = mt + f*16 + kg*4 + ri;
      if (r < cnt) {
        int tok = sh ? r : tok_list[off + r];
        float* op = out + (size_t)tok * D_MODEL + c0;
        atomicAdd(op, ac0[f][ri]);
        atomicAdd(op + 16, ac1[f][ri]);
      }
    }
}

// ---------------- host ----------------
extern "C" void kernel_launch(void* const* d_in, const int* in_sizes, int n_in,
                              void* d_out, int out_size, void* d_ws, size_t ws_size,
                              hipStream_t stream) {
  const float* x     = (const float*)d_in[0];
  const float* fcos  = (const float*)d_in[1];
  const float* fsin  = (const float*)d_in[2];
  const float* anw   = (const float*)d_in[3];
  const float* fnw   = (const float*)d_in[4];
  const float* wq    = (const float*)d_in[5];
  const float* wk    = (const float*)d_in[6];
  const float* wvv   = (const float*)d_in[7];
  const float* wo    = (const float*)d_in[8];
  const float* qnw   = (const float*)d_in[9];
  const float* knw   = (const float*)d_in[10];
  const float* gatew = (const float*)d_in[11];
  const float* w1e   = (const float*)d_in[12];
  const float* w3e   = (const float*)d_in[13];
  const float* w2e   = (const float*)d_in[14];
  const float* sw1   = (const float*)d_in[15];
  const float* sw3   = (const float*)d_in[16];
  const float* sw2   = (const float*)d_in[17];
  float* out = (float*)d_out;

  char* ws = (char*)d_ws;
  const size_t MB = 1ull << 20;
  float*  hx    = (float*)(ws);             // 4MB (attn-norm out, then attn out)
  float*  h     = (float*)(ws + 4*MB);      // 4MB residual after attention
  float*  z     = (float*)(ws + 8*MB);      // 4MB ffn-norm out (f32, for gate)
  float*  qbuf  = (float*)(ws + 12*MB);     // 4MB (dead after attention)
  float*  kbuf  = (float*)(ws + 16*MB);     // 1MB
  float*  vbuf  = (float*)(ws + 17*MB);     // 1MB
  ushort* zb    = (ushort*)(ws + 12*MB);    // 2MB bf16 z (overlaps dead qbuf)
  ushort* gb    = (ushort*)(ws + 14*MB);    // 6.3MB bf16 expert activations
  ushort* s_gb  = (ushort*)(ws + 20*MB + 512*1024); // 1MB shared-expert act
  char*   misc  = ws + 22*MB;
  int*   sel      = (int*)(misc);
  float* topw     = (float*)(misc + 24576);
  int*   counts   = (int*)(misc + 49152);
  int*   offs     = (int*)(misc + 49408);
  int*   cursor   = (int*)(misc + 49664);
  int*   ntiles   = (int*)(misc + 50432);
  int*   tile2e   = (int*)(misc + 50688);
  int*   tile2mt  = (int*)(misc + 51200);
  int*   tok_list = (int*)(misc + 51712);
  float* wt_list  = (float*)(misc + 76288);

  // 1. attn rmsnorm
  rmsnorm_k<<<SEQ, 256, 0, stream>>>(x, anw, hx, nullptr);
  // 2. QKV projections
  mfma_gemm_k<<<dim3(8, 64), 256, 0, stream>>>(hx, wq, qbuf, nullptr, nullptr, 1024, 1024);
  mfma_gemm_k<<<dim3(2, 64), 256, 0, stream>>>(hx, wk, kbuf, nullptr, nullptr, 256, 1024);
  mfma_gemm_k<<<dim3(2, 64), 256, 0, stream>>>(hx, wvv, vbuf, nullptr, nullptr, 256, 1024);
  // 3. q/k rmsnorm + rope
  qknorm_rope_k<<<dim3(SEQ, NHEADS + NKVH), 64, 0, stream>>>(qbuf, kbuf, qnw, knw, fcos, fsin);
  // 4. causal flash attention v2 (32-row blocks, reversed order) -> hx
  attn_mfma2<<<dim3(SEQ / 32, NHEADS), 128, 0, stream>>>(qbuf, kbuf, vbuf, hx);
  // 5. o @ wo + x -> h (and d_out = h)
  mfma_gemm_k<<<dim3(8, 64), 256, 0, stream>>>(hx, wo, h, out, x, 1024, 1024);
  // 6. ffn rmsnorm -> z (f32) + zb (bf16)
  rmsnorm_k<<<SEQ, 256, 0, stream>>>(h, fnw, z, zb);
  // 7. gate + top-k + bucketing + flattened tile list (incl. shared tiles)
  hipMemsetAsync(counts, 0, 256, stream);
  gate_topk_k<<<SEQ, 64, 0, stream>>>(z, gatew, sel, topw, counts);
  scan_k<<<1, 64, 0, stream>>>(counts, offs, cursor, tile2e, tile2mt, ntiles);
  scatter_k<<<SEQ / 256, 256, 0, stream>>>(sel, topw, cursor, tok_list, wt_list);
  // 8. MoE phase A (experts + shared expert in one dispatch)
  moe_up6<<<dim3(HEXP / 64, MAXTILES), 256, 0, stream>>>(zb, w1e, w3e,
      (size_t)D_MODEL * HEXP, sw1, sw3, gb, s_gb, tok_list, wt_list,
      counts, offs, tile2e, tile2mt, ntiles);
  // 9. MoE phase B (experts + shared expert in one dispatch)
  moe_down6<<<dim3(D_MODEL / 128, MAXTILES), 256, 0, stream>>>(gb, s_gb, w2e,
      (size_t)HEXP * D_MODEL, sw2, out, tok_list, counts, offs,
      tile2e, tile2mt, ntiles);
  (void)in_sizes; (void)n_in; (void)out_size; (void)ws_size;
}

// Round 14
// 340.243 us; speedup vs baseline: 1.6226x; 1.2328x over previous
//
#include <hip/hip_runtime.h>
#include <hip/hip_bf16.h>
#include <math.h>

#define D_MODEL 1024
#define SEQ     1024
#define NHEADS  16
#define NKVH    4
#define HDIM    64
#define NEXP    64
#define TOPK    6
#define HEXP    512
#define EPS     1e-5f
#define MAXTILES 120   // 112 expert tiles max + 8 shared-expert tiles

typedef __attribute__((ext_vector_type(8))) short bf16x8;
typedef __attribute__((ext_vector_type(4))) float f32x4;

struct bfrag2 { bf16x8 hi, lo; };
struct f32x8r { float v[8]; };

__device__ __forceinline__ unsigned rne1(float a) {
  union { float f; unsigned u; } x; x.f = a;
  return (x.u + 0x7fffu + ((x.u >> 16) & 1u)) >> 16;
}
__device__ __forceinline__ float frombf(unsigned h) {
  union { float f; unsigned u; } x; x.u = h << 16; return x.f;
}
__device__ __forceinline__ void split_pack(float a, float b, unsigned& hi, unsigned& lo) {
  unsigned ha = rne1(a), hb = rne1(b);
  hi = ha | (hb << 16);
  lo = rne1(a - frombf(ha)) | (rne1(b - frombf(hb)) << 16);
}
__device__ __forceinline__ unsigned pk2bf(float a, float b) {
  return rne1(a) | (rne1(b) << 16);
}

__device__ __forceinline__ f32x4 mfma16(bf16x8 a, bf16x8 b, f32x4 c) {
  return __builtin_amdgcn_mfma_f32_16x16x32_bf16(a, b, c, 0, 0, 0);
}
__device__ __forceinline__ f32x4 mfma_sp(bf16x8 ah, bf16x8 al, const bfrag2& b, f32x4 c) {
  c = mfma16(ah, b.hi, c);
  c = mfma16(ah, b.lo, c);
  c = mfma16(al, b.hi, c);
  return c;
}

// barrier WITHOUT the compiler's vmcnt(0) drain: LDS ordered, global loads in flight
__device__ __forceinline__ void barrier_nv() {
  asm volatile("s_waitcnt lgkmcnt(0)" ::: "memory");
  __builtin_amdgcn_s_barrier();
}

__device__ __forceinline__ f32x8r loadraw8(const float* __restrict__ p, int ld) {
  f32x8r r;
#pragma unroll
  for (int i = 0; i < 8; i++) r.v[i] = p[(size_t)ld * i];
  return r;
}
__device__ __forceinline__ bfrag2 cvt_bf2(const f32x8r& f) {
  union { bf16x8 v; unsigned u[4]; } H, L;
  split_pack(f.v[0], f.v[1], H.u[0], L.u[0]);
  split_pack(f.v[2], f.v[3], H.u[1], L.u[1]);
  split_pack(f.v[4], f.v[5], H.u[2], L.u[2]);
  split_pack(f.v[6], f.v[7], H.u[3], L.u[3]);
  bfrag2 r; r.hi = H.v; r.lo = L.v; return r;
}
__device__ __forceinline__ bf16x8 cvt_bf(const f32x8r& f) {
  union { bf16x8 v; unsigned u[4]; } r;
  r.u[0] = pk2bf(f.v[0], f.v[1]); r.u[1] = pk2bf(f.v[2], f.v[3]);
  r.u[2] = pk2bf(f.v[4], f.v[5]); r.u[3] = pk2bf(f.v[6], f.v[7]);
  return r.v;
}
template<int RL>
__device__ __forceinline__ bf16x8 bfrag_lds(const ushort* __restrict__ B, int akb, int c) {
  union { bf16x8 v; ushort s[8]; } r;
#pragma unroll
  for (int j = 0; j < 8; j++) r.s[j] = B[(akb + j) * RL + c];
  return r.v;
}

// ---------------- rmsnorm over D=1024 (+ optional bf16 copy) ----------------
__global__ __launch_bounds__(256) void rmsnorm_k(const float* __restrict__ x,
    const float* __restrict__ w, float* __restrict__ out, ushort* __restrict__ outb) {
  int t = blockIdx.x;
  const float4* xr = (const float4*)(x + (size_t)t * D_MODEL);
  float4 v = xr[threadIdx.x];
  float ss = v.x*v.x + v.y*v.y + v.z*v.z + v.w*v.w;
  for (int off = 32; off; off >>= 1) ss += __shfl_xor(ss, off);
  __shared__ float red[4];
  if ((threadIdx.x & 63) == 0) red[threadIdx.x >> 6] = ss;
  __syncthreads();
  float tot = red[0] + red[1] + red[2] + red[3];
  float inv = rsqrtf(tot * (1.f / D_MODEL) + EPS);
  float4 wv = ((const float4*)w)[threadIdx.x];
  float4 o;
  o.x = v.x * inv * wv.x; o.y = v.y * inv * wv.y;
  o.z = v.z * inv * wv.z; o.w = v.w * inv * wv.w;
  ((float4*)(out + (size_t)t * D_MODEL))[threadIdx.x] = o;
  if (outb) {
    uint2 b;
    b.x = pk2bf(o.x, o.y); b.y = pk2bf(o.z, o.w);
    *(uint2*)(outb + (size_t)t * D_MODEL + threadIdx.x * 4) = b;
  }
}

// ---------------- fused QKV GEMM, plain bf16, depth-2, relaxed barrier -------------
// grid = (12, 64): x<8 -> wq cols, 8..9 -> wk, 10..11 -> wv. K=1024 fixed.
__global__ __launch_bounds__(256) void mfma_gemm_qkv(const float* __restrict__ A,
    const float* __restrict__ WQ, const float* __restrict__ WK,
    const float* __restrict__ WV, float* __restrict__ Q, float* __restrict__ Kb,
    float* __restrict__ V) {
  const float* B; float* C; int N, bn;
  int bx = blockIdx.x;
  if (bx < 8)       { B = WQ; C = Q;  N = 1024; bn = bx << 7; }
  else if (bx < 10) { B = WK; C = Kb; N = 256;  bn = (bx - 8) << 7; }
  else              { B = WV; C = V;  N = 256;  bn = (bx - 10) << 7; }
  const int K = 1024;
  __shared__ short Ah[2][16][40];
  int bm = blockIdx.y << 4;
  int tid = threadIdx.x, wv = tid >> 6, lane = tid & 63;
  int m_ = tid >> 4, k_ = (tid & 15) << 1;
  int arow = lane & 15, akb = (lane >> 4) << 3;
  int c0 = bn + wv * 32 + arow;
  const float* ar = A + (size_t)(bm + m_) * K + k_;
  {
    float2 a0 = *(const float2*)ar;
    *(unsigned*)&Ah[0][m_][k_] = pk2bf(a0.x, a0.y);
  }
  float2 aO = *(const float2*)(ar + 32);
  float2 aE;
  f32x8r bE0 = loadraw8(B + (size_t)akb * N + c0, N);
  f32x8r bE1 = loadraw8(B + (size_t)akb * N + c0 + 16, N);
  f32x8r bO0 = loadraw8(B + (size_t)(32 + akb) * N + c0, N);
  f32x8r bO1 = loadraw8(B + (size_t)(32 + akb) * N + c0 + 16, N);
  __syncthreads();
  f32x4 acc0 = {0.f,0.f,0.f,0.f}, acc1 = {0.f,0.f,0.f,0.f};
  for (int k0 = 0; k0 < K; k0 += 64) {
    { // even
      int kp = (k0 + 64 < K) ? k0 + 64 : 0;
      f32x8r n0 = loadraw8(B + (size_t)(kp + akb) * N + c0, N);
      f32x8r n1 = loadraw8(B + (size_t)(kp + akb) * N + c0 + 16, N);
      float2 an = *(const float2*)(ar + kp);
      bf16x8 f0 = cvt_bf(bE0), f1 = cvt_bf(bE1);
      bf16x8 ah = *(const bf16x8*)&Ah[0][arow][akb];
      acc0 = mfma16(ah, f0, acc0);
      acc1 = mfma16(ah, f1, acc1);
      *(unsigned*)&Ah[1][m_][k_] = pk2bf(aO.x, aO.y);
      barrier_nv();
      bE0 = n0; bE1 = n1; aE = an;
    }
    { // odd
      int kp = (k0 + 96 < K) ? k0 + 96 : 0;
      f32x8r n0 = loadraw8(B + (size_t)(kp + akb) * N + c0, N);
      f32x8r n1 = loadraw8(B + (size_t)(kp + akb) * N + c0 + 16, N);
      float2 an = *(const float2*)(ar + kp);
      bf16x8 f0 = cvt_bf(bO0), f1 = cvt_bf(bO1);
      bf16x8 ah = *(const bf16x8*)&Ah[1][arow][akb];
      acc0 = mfma16(ah, f0, acc0);
      acc1 = mfma16(ah, f1, acc1);
      *(unsigned*)&Ah[0][m_][k_] = pk2bf(aE.x, aE.y);
      barrier_nv();
      bO0 = n0; bO1 = n1; aO = an;
    }
  }
  int r0 = (lane >> 4) << 2;
#pragma unroll
  for (int ri = 0; ri < 4; ri++) {
    size_t o0 = (size_t)(bm + r0 + ri) * N + c0;
    C[o0] = acc0[ri];
    C[o0 + 16] = acc1[ri];
  }
}

// ---------------- dense split-bf16 MFMA GEMM (wo), depth-2, relaxed barrier --------
__global__ __launch_bounds__(256) void mfma_gemm_k(const float* __restrict__ A,
    const float* __restrict__ B, float* __restrict__ C, float* __restrict__ C2,
    const float* __restrict__ resid, int N, int K) {
  __shared__ short Ah[2][16][40];
  __shared__ short Al[2][16][40];
  int bm = blockIdx.y << 4, bn = blockIdx.x << 7;
  int tid = threadIdx.x, wv = tid >> 6, lane = tid & 63;
  int m_ = tid >> 4, k_ = (tid & 15) << 1;
  int arow = lane & 15, akb = (lane >> 4) << 3;
  int c0 = bn + wv * 32 + arow;
  const float* ar = A + (size_t)(bm + m_) * K + k_;
  {
    float2 a0 = *(const float2*)ar;
    unsigned hi, lo; split_pack(a0.x, a0.y, hi, lo);
    *(unsigned*)&Ah[0][m_][k_] = hi;
    *(unsigned*)&Al[0][m_][k_] = lo;
  }
  float2 aO = *(const float2*)(ar + 32);
  float2 aE;
  f32x8r bE0 = loadraw8(B + (size_t)akb * N + c0, N);
  f32x8r bE1 = loadraw8(B + (size_t)akb * N + c0 + 16, N);
  f32x8r bO0 = loadraw8(B + (size_t)(32 + akb) * N + c0, N);
  f32x8r bO1 = loadraw8(B + (size_t)(32 + akb) * N + c0 + 16, N);
  __syncthreads();
  f32x4 acc0 = {0.f,0.f,0.f,0.f}, acc1 = {0.f,0.f,0.f,0.f};
  for (int k0 = 0; k0 < K; k0 += 64) {
    {
      int kp = (k0 + 64 < K) ? k0 + 64 : 0;
      f32x8r n0 = loadraw8(B + (size_t)(kp + akb) * N + c0, N);
      f32x8r n1 = loadraw8(B + (size_t)(kp + akb) * N + c0 + 16, N);
      float2 an = *(const float2*)(ar + kp);
      bfrag2 f0 = cvt_bf2(bE0), f1 = cvt_bf2(bE1);
      bf16x8 ah = *(const bf16x8*)&Ah[0][arow][akb];
      bf16x8 al = *(const bf16x8*)&Al[0][arow][akb];
      acc0 = mfma_sp(ah, al, f0, acc0);
      acc1 = mfma_sp(ah, al, f1, acc1);
      unsigned hi, lo; split_pack(aO.x, aO.y, hi, lo);
      *(unsigned*)&Ah[1][m_][k_] = hi;
      *(unsigned*)&Al[1][m_][k_] = lo;
      barrier_nv();
      bE0 = n0; bE1 = n1; aE = an;
    }
    {
      int kp = (k0 + 96 < K) ? k0 + 96 : 0;
      f32x8r n0 = loadraw8(B + (size_t)(kp + akb) * N + c0, N);
      f32x8r n1 = loadraw8(B + (size_t)(kp + akb) * N + c0 + 16, N);
      float2 an = *(const float2*)(ar + kp);
      bfrag2 f0 = cvt_bf2(bO0), f1 = cvt_bf2(bO1);
      bf16x8 ah = *(const bf16x8*)&Ah[1][arow][akb];
      bf16x8 al = *(const bf16x8*)&Al[1][arow][akb];
      acc0 = mfma_sp(ah, al, f0, acc0);
      acc1 = mfma_sp(ah, al, f1, acc1);
      unsigned hi, lo; split_pack(aE.x, aE.y, hi, lo);
      *(unsigned*)&Ah[0][m_][k_] = hi;
      *(unsigned*)&Al[0][m_][k_] = lo;
      barrier_nv();
      bO0 = n0; bO1 = n1; aO = an;
    }
  }
  int r0 = (lane >> 4) << 2;
#pragma unroll
  for (int ri = 0; ri < 4; ri++) {
    int row = bm + r0 + ri;
    size_t o0 = (size_t)row * N + c0;
    float v0 = acc0[ri], v1 = acc1[ri];
    if (resid) { v0 += resid[o0]; v1 += resid[o0 + 16]; }
    C[o0] = v0; C[o0 + 16] = v1;
    if (C2) { C2[o0] = v0; C2[o0 + 16] = v1; }
  }
}

// ---------------- per-head rmsnorm + RoPE ----------------
__global__ __launch_bounds__(64) void qknorm_rope_k(float* __restrict__ qb,
    float* __restrict__ kb, const float* __restrict__ qw, const float* __restrict__ kw,
    const float* __restrict__ fcos, const float* __restrict__ fsin) {
  int t = blockIdx.x, hid = blockIdx.y, lane = threadIdx.x;
  float* p; const float* w;
  if (hid < NHEADS) { p = qb + (size_t)t * (NHEADS*HDIM) + hid * HDIM; w = qw; }
  else              { p = kb + (size_t)t * (NKVH*HDIM) + (hid - NHEADS) * HDIM; w = kw; }
  float v = p[lane];
  float ss = v * v;
  for (int off = 32; off; off >>= 1) ss += __shfl_xor(ss, off);
  float vn = v * rsqrtf(ss * (1.f / HDIM) + EPS) * w[lane];
  int pi = lane >> 1;
  float c = fcos[t * (HDIM/2) + pi], s = fsin[t * (HDIM/2) + pi];
  float other = __shfl_xor(vn, 1);
  float o = (lane & 1) ? (other * s + vn * c) : (vn * c - other * s);
  p[lane] = o;
}

// ---------------- causal flash attention (r8 geometry + vec staging + reversal) ----
// grid = (SEQ/64, NHEADS), 256 thr (4 waves); block = 1 head x 64 q-rows.
__global__ __launch_bounds__(256) void attn_mfma(const float* __restrict__ qb,
    const float* __restrict__ kb, const float* __restrict__ vb, float* __restrict__ ob) {
  int h = blockIdx.y;
  int qbase = ((SEQ / 64 - 1) - blockIdx.x) << 6;   // heaviest first
  int kvh = h >> 2;
  int tid = threadIdx.x, wv = tid >> 6, lane = tid & 63;
  __shared__ short Kt[64][72];
  __shared__ short Vt[64][72];
  __shared__ short Pl[4][16][72];
  int arow = lane & 15;
  int akb = (lane >> 4) << 3;
  int kg = lane >> 4;
  int qrow_base = qbase + wv * 16;
  bf16x8 qf[2];
  {
    const float* qp = qb + (size_t)(qrow_base + arow) * (NHEADS*HDIM) + h * HDIM;
#pragma unroll
    for (int c = 0; c < 2; c++) {
      int d0 = akb + c * 32;
      union { bf16x8 v; unsigned u[4]; } r;
#pragma unroll
      for (int j = 0; j < 4; j++) r.u[j] = pk2bf(qp[d0 + 2*j], qp[d0 + 2*j + 1]);
      qf[c] = r.v;
    }
  }
  f32x4 accO[4];
  float m_[4], l_[4];
#pragma unroll
  for (int n = 0; n < 4; n++) { accO[n] = (f32x4){0.f,0.f,0.f,0.f}; m_[n] = -1e30f; l_[n] = 0.f; }
  int ntiles = (qbase >> 6) + 1;
  for (int ti = 0; ti < ntiles; ti++) {
    int ts = ti << 6;
    // stage K [key][d] / V transposed [d][key] via float4 loads
#pragma unroll
    for (int i = 0; i < 4; i++) {
      int f = tid + i * 256;          // f4 index in [0,1024)
      int kk = f >> 4, d4 = (f & 15) << 2;
      size_t src = (size_t)(ts + kk) * (NKVH*HDIM) + kvh * HDIM + d4;
      float4 k4 = *(const float4*)(kb + src);
      float4 v4 = *(const float4*)(vb + src);
      unsigned* kd = (unsigned*)&Kt[kk][d4];
      kd[0] = pk2bf(k4.x, k4.y);
      kd[1] = pk2bf(k4.z, k4.w);
      Vt[d4 + 0][kk] = (short)rne1(v4.x);
      Vt[d4 + 1][kk] = (short)rne1(v4.y);
      Vt[d4 + 2][kk] = (short)rne1(v4.z);
      Vt[d4 + 3][kk] = (short)rne1(v4.w);
    }
    __syncthreads();
    f32x4 accS[4];
#pragma unroll
    for (int n = 0; n < 4; n++) accS[n] = (f32x4){0.f,0.f,0.f,0.f};
#pragma unroll
    for (int c = 0; c < 2; c++) {
#pragma unroll
      for (int n = 0; n < 4; n++) {
        bf16x8 bf = *(const bf16x8*)&Kt[n*16 + arow][c*32 + akb];
        accS[n] = mfma16(qf[c], bf, accS[n]);
      }
    }
#pragma unroll
    for (int ri = 0; ri < 4; ri++) {
      int qrow = qrow_base + kg*4 + ri;
      float mx = -1e30f;
#pragma unroll
      for (int n = 0; n < 4; n++) {
        int key = ts + n*16 + arow;
        float s = (key <= qrow) ? accS[n][ri] * 0.125f : -1e30f;
        accS[n][ri] = s;
        mx = fmaxf(mx, s);
      }
      for (int off = 1; off < 16; off <<= 1) mx = fmaxf(mx, __shfl_xor(mx, off));
      float mn = fmaxf(m_[ri], mx);
      float a = __expf(m_[ri] - mn);
      float sum = 0.f;
#pragma unroll
      for (int n = 0; n < 4; n++) {
        float p = __expf(accS[n][ri] - mn);
        accS[n][ri] = p;
        sum += p;
      }
      for (int off = 1; off < 16; off <<= 1) sum += __shfl_xor(sum, off);
      l_[ri] = l_[ri] * a + sum;
      m_[ri] = mn;
#pragma unroll
      for (int n = 0; n < 4; n++) accO[n][ri] *= a;
    }
#pragma unroll
    for (int ri = 0; ri < 4; ri++)
#pragma unroll
      for (int n = 0; n < 4; n++)
        Pl[wv][kg*4 + ri][n*16 + arow] = (short)rne1(accS[n][ri]);
#pragma unroll
    for (int c = 0; c < 2; c++) {
      bf16x8 pf = *(const bf16x8*)&Pl[wv][arow][c*32 + akb];
#pragma unroll
      for (int n = 0; n < 4; n++) {
        bf16x8 vf = *(const bf16x8*)&Vt[n*16 + arow][c*32 + akb];
        accO[n] = mfma16(pf, vf, accO[n]);
      }
    }
    __syncthreads();
  }
#pragma unroll
  for (int ri = 0; ri < 4; ri++) {
    int qrow = qrow_base + kg*4 + ri;
    float inv = 1.f / l_[ri];
#pragma unroll
    for (int n = 0; n < 4; n++)
      ob[(size_t)qrow * (NHEADS*HDIM) + h * HDIM + n*16 + arow] = accO[n][ri] * inv;
  }
}

// ---------------- gate: softmax -> top-6 (low-index tie-break) ----------------
__global__ __launch_bounds__(64) void gate_topk_k(const float* __restrict__ z,
    const float* __restrict__ gw, int* __restrict__ sel, float* __restrict__ topw,
    int* __restrict__ counts) {
  int t = blockIdx.x, lane = threadIdx.x;
  const float* zr = z + (size_t)t * D_MODEL;
  float acc = 0.f;
  for (int d = 0; d < D_MODEL; d += 4) {
    float4 zv = *(const float4*)(zr + d);
    acc += zv.x * gw[(size_t)(d + 0) * NEXP + lane];
    acc += zv.y * gw[(size_t)(d + 1) * NEXP + lane];
    acc += zv.z * gw[(size_t)(d + 2) * NEXP + lane];
    acc += zv.w * gw[(size_t)(d + 3) * NEXP + lane];
  }
  float m = acc;
  for (int off = 32; off; off >>= 1) m = fmaxf(m, __shfl_xor(m, off));
  float p = __expf(acc - m);
  float s = p;
  for (int off = 32; off; off >>= 1) s += __shfl_xor(s, off);
  p /= s;
  float rem = p, wsum = 0.f;
  float wvv[TOPK]; int wi[TOPK];
  for (int i = 0; i < TOPK; i++) {
    float v = rem; int idx = lane;
    for (int off = 32; off; off >>= 1) {
      float v2 = __shfl_xor(v, off);
      int i2 = __shfl_xor(idx, off);
      if (v2 > v || (v2 == v && i2 < idx)) { v = v2; idx = i2; }
    }
    wvv[i] = v; wi[i] = idx; wsum += v;
    if (lane == idx) rem = -1.f;
  }
  if (lane < TOPK) {
    sel[t * TOPK + lane] = wi[lane];
    topw[t * TOPK + lane] = wvv[lane] / wsum;
  }
  if (lane == 0)
    for (int i = 0; i < TOPK; i++) atomicAdd(&counts[wi[i]], 1);
}

// ---------------- scan + flattened (expert, mtile) work list (+shared tiles) -------
__global__ void scan_k(const int* __restrict__ counts, int* __restrict__ offs,
                       int* __restrict__ cursor, int* __restrict__ tile2e,
                       int* __restrict__ tile2mt, int* __restrict__ ntiles) {
  int lane = threadIdx.x;
  int c = counts[lane];
  int x = c;
  for (int off = 1; off < 64; off <<= 1) {
    int y = __shfl_up(x, off);
    if (lane >= off) x += y;
  }
  offs[lane] = x - c;
  cursor[lane] = x - c;
  int nt = (c + 127) >> 7;
  int y = nt;
  for (int off = 1; off < 64; off <<= 1) {
    int t2 = __shfl_up(y, off);
    if (lane >= off) y += t2;
  }
  int tbase = y - nt;
  for (int i = 0; i < nt; i++) { tile2e[tbase + i] = lane; tile2mt[tbase + i] = i; }
  if (lane == 63) {
    for (int i = 0; i < 8; i++) { tile2e[y + i] = NEXP; tile2mt[y + i] = i; }
    ntiles[0] = y + 8;
  }
}

__global__ void scatter_k(const int* __restrict__ sel, const float* __restrict__ topw,
    int* __restrict__ cursor, int* __restrict__ tok, float* __restrict__ wt) {
  int t = blockIdx.x * 256 + threadIdx.x;
  if (t >= SEQ) return;
  for (int i = 0; i < TOPK; i++) {
    int e = sel[t * TOPK + i];
    int pos = atomicAdd(&cursor[e], 1);
    tok[pos] = t;
    wt[pos] = topw[t * TOPK + i];
  }
}

// ---------------- MoE phase A (r8): coalesced-LDS B, relaxed barrier, dbuf ---------
__global__ __launch_bounds__(256) void moe_up6(const ushort* __restrict__ zb,
    const float* __restrict__ w1, const float* __restrict__ w3, size_t wstride,
    const float* __restrict__ sw1, const float* __restrict__ sw3,
    ushort* __restrict__ g, ushort* __restrict__ sg,
    const int* __restrict__ tok_list, const float* __restrict__ wt_list,
    const int* __restrict__ counts, const int* __restrict__ offs,
    const int* __restrict__ tile2e, const int* __restrict__ tile2mt,
    const int* __restrict__ ntiles) {
  int gt = blockIdx.y;
  if (gt >= ntiles[0]) return;
  int e = tile2e[gt];
  int mt = tile2mt[gt] << 7;
  bool sh = (e == NEXP);
  int cnt = sh ? SEQ : counts[e];
  int off = sh ? 0 : offs[e];
  const float* w1p = (sh ? sw1 : w1 + (size_t)e * wstride) + (blockIdx.x << 6);
  const float* w3p = (sh ? sw3 : w3 + (size_t)e * wstride) + (blockIdx.x << 6);
  ushort* gout = sh ? sg : g;
  __shared__ ushort Ah[2][128][40];
  __shared__ ushort Bs[2][2][32][74];
  __shared__ int toks[128];
  int tid = threadIdx.x, wv = tid >> 6, lane = tid & 63;
  int arow = lane & 15, akb = (lane >> 4) << 3, kg = lane >> 4;
  int c0l = wv * 16 + arow;
  int c0 = (blockIdx.x << 6) + c0l;
  if (tid < 128) {
    int r = mt + tid; if (r >= cnt) r = cnt - 1;
    toks[tid] = sh ? r : tok_list[off + r];
  }
  __syncthreads();
  int row0 = tid >> 2, q8 = (tid & 3) << 3, row1 = row0 + 64;
  const ushort* zr0 = zb + (size_t)toks[row0] * D_MODEL + q8;
  const ushort* zr1 = zb + (size_t)toks[row1] * D_MODEL + q8;
  int kB = tid >> 4, cB = (tid & 15) << 2;
  const float* w1q = w1p + (size_t)kB * HEXP + cB;
  const float* w3q = w3p + (size_t)kB * HEXP + cB;
  uint4  ra0 = *(const uint4*)zr0;
  uint4  ra1 = *(const uint4*)zr1;
  float4 rb1a = *(const float4*)w1q;
  float4 rb1b = *(const float4*)(w1q + 16 * HEXP);
  float4 rb3a = *(const float4*)w3q;
  float4 rb3b = *(const float4*)(w3q + 16 * HEXP);
  f32x4 a1[8], a3[8];
#pragma unroll
  for (int f = 0; f < 8; f++) { a1[f] = (f32x4){0.f,0.f,0.f,0.f}; a3[f] = (f32x4){0.f,0.f,0.f,0.f}; }
  int cur = 0;
  for (int k0 = 0; k0 < D_MODEL; k0 += 32) {
    int kp = (k0 + 32 < D_MODEL) ? k0 + 32 : 0;
    uint4  na0 = *(const uint4*)(zr0 + kp);
    uint4  na1 = *(const uint4*)(zr1 + kp);
    const float* w1n = w1q + (size_t)kp * HEXP;
    const float* w3n = w3q + (size_t)kp * HEXP;
    float4 nb1a = *(const float4*)w1n;
    float4 nb1b = *(const float4*)(w1n + 16 * HEXP);
    float4 nb3a = *(const float4*)w3n;
    float4 nb3b = *(const float4*)(w3n + 16 * HEXP);
    *(uint4*)&Ah[cur][row0][q8] = ra0;
    *(uint4*)&Ah[cur][row1][q8] = ra1;
    {
      unsigned* p = (unsigned*)&Bs[cur][0][kB][cB];
      p[0] = pk2bf(rb1a.x, rb1a.y); p[1] = pk2bf(rb1a.z, rb1a.w);
      unsigned* p2 = (unsigned*)&Bs[cur][0][kB + 16][cB];
      p2[0] = pk2bf(rb1b.x, rb1b.y); p2[1] = pk2bf(rb1b.z, rb1b.w);
      unsigned* p3 = (unsigned*)&Bs[cur][1][kB][cB];
      p3[0] = pk2bf(rb3a.x, rb3a.y); p3[1] = pk2bf(rb3a.z, rb3a.w);
      unsigned* p4 = (unsigned*)&Bs[cur][1][kB + 16][cB];
      p4[0] = pk2bf(rb3b.x, rb3b.y); p4[1] = pk2bf(rb3b.z, rb3b.w);
    }
    barrier_nv();
    bf16x8 f1 = bfrag_lds<74>(&Bs[cur][0][0][0], akb, c0l);
    bf16x8 f3 = bfrag_lds<74>(&Bs[cur][1][0][0], akb, c0l);
#pragma unroll
    for (int f = 0; f < 8; f++) {
      bf16x8 ah = *(const bf16x8*)&Ah[cur][f*16 + arow][akb];
      a1[f] = mfma16(ah, f1, a1[f]);
      a3[f] = mfma16(ah, f3, a3[f]);
    }
    ra0 = na0; ra1 = na1;
    rb1a = nb1a; rb1b = nb1b; rb3a = nb3a; rb3b = nb3b;
    cur ^= 1;
  }
#pragma unroll
  for (int f = 0; f < 8; f++)
#pragma unroll
    for (int ri = 0; ri < 4; ri++) {
      int r = mt + f*16 + kg*4 + ri;
      if (r < cnt) {
        float wt = sh ? 1.0f : wt_list[off + r];
        float h1 = a1[f][ri], h3 = a3[f][ri];
        float gv = h1 / (1.f + __expf(-h1)) * h3 * wt;
        gout[(size_t)(off + r) * HEXP + c0] = (ushort)rne1(gv);
      }
    }
}

// ---------------- MoE phase B (r8): coalesced-LDS B, relaxed barrier, dbuf ---------
__global__ __launch_bounds__(256) void moe_down6(const ushort* __restrict__ g,
    const ushort* __restrict__ sg, const float* __restrict__ w2, size_t wstride,
    const float* __restrict__ sw2, float* __restrict__ out,
    const int* __restrict__ tok_list, const int* __restrict__ counts,
    const int* __restrict__ offs, const int* __restrict__ tile2e,
    const int* __restrict__ tile2mt, const int* __restrict__ ntiles) {
  int gt = blockIdx.y;
  if (gt >= ntiles[0]) return;
  int e = tile2e[gt];
  int mt = tile2mt[gt] << 7;
  bool sh = (e == NEXP);
  int cnt = sh ? SEQ : counts[e];
  int off = sh ? 0 : offs[e];
  const float* w2p = (sh ? sw2 : w2 + (size_t)e * wstride) + (blockIdx.x << 7);
  const ushort* gin = sh ? sg : g;
  __shared__ ushort Ah[2][128][40];
  __shared__ ushort Bs[2][32][138];
  int tid = threadIdx.x, wv = tid >> 6, lane = tid & 63;
  int arow = lane & 15, akb = (lane >> 4) << 3, kg = lane >> 4;
  int c0l = wv * 32 + arow;
  int c0 = (blockIdx.x << 7) + c0l;
  int row0 = tid >> 2, q8 = (tid & 3) << 3, row1 = row0 + 64;
  int rr0 = mt + row0; if (rr0 >= cnt) rr0 = cnt - 1;
  int rr1 = mt + row1; if (rr1 >= cnt) rr1 = cnt - 1;
  const ushort* gr0 = gin + (size_t)(off + rr0) * HEXP + q8;
  const ushort* gr1 = gin + (size_t)(off + rr1) * HEXP + q8;
  int kB = tid >> 3, cB = (tid & 7) << 4;
  const float* w2q = w2p + (size_t)kB * D_MODEL + cB;
  uint4  ra0 = *(const uint4*)gr0;
  uint4  ra1 = *(const uint4*)gr1;
  float4 rb0 = *(const float4*)(w2q);
  float4 rb1 = *(const float4*)(w2q + 4);
  float4 rb2 = *(const float4*)(w2q + 8);
  float4 rb3 = *(const float4*)(w2q + 12);
  f32x4 ac0[8], ac1[8];
#pragma unroll
  for (int f = 0; f < 8; f++) { ac0[f] = (f32x4){0.f,0.f,0.f,0.f}; ac1[f] = (f32x4){0.f,0.f,0.f,0.f}; }
  int cur = 0;
  for (int k0 = 0; k0 < HEXP; k0 += 32) {
    int kp = (k0 + 32 < HEXP) ? k0 + 32 : 0;
    uint4  na0 = *(const uint4*)(gr0 + kp);
    uint4  na1 = *(const uint4*)(gr1 + kp);
    const float* wn = w2q + (size_t)kp * D_MODEL;
    float4 nb0 = *(const float4*)(wn);
    float4 nb1 = *(const float4*)(wn + 4);
    float4 nb2 = *(const float4*)(wn + 8);
    float4 nb3 = *(const float4*)(wn + 12);
    *(uint4*)&Ah[cur][row0][q8] = ra0;
    *(uint4*)&Ah[cur][row1][q8] = ra1;
    {
      unsigned* p = (unsigned*)&Bs[cur][kB][cB];
      p[0] = pk2bf(rb0.x, rb0.y); p[1] = pk2bf(rb0.z, rb0.w);
      p[2] = pk2bf(rb1.x, rb1.y); p[3] = pk2bf(rb1.z, rb1.w);
      p[4] = pk2bf(rb2.x, rb2.y); p[5] = pk2bf(rb2.z, rb2.w);
      p[6] = pk2bf(rb3.x, rb3.y); p[7] = pk2bf(rb3.z, rb3.w);
    }
    barrier_nv();
    bf16x8 f0 = bfrag_lds<138>(&Bs[cur][0][0], akb, c0l);
    bf16x8 f1 = bfrag_lds<138>(&Bs[cur][0][0], akb, c0l + 16);
#pragma unroll
    for (int f = 0; f < 8; f++) {
      bf16x8 ah = *(const bf16x8*)&Ah[cur][f*16 + arow][akb];
      ac0[f] = mfma16(ah, f0, ac0[f]);
      ac1[f] = mfma16(ah, f1, ac1[f]);
    }
    ra0 = na0; ra1 = na1;
    rb0 = nb0; rb1 = nb1; rb2 = nb2; rb3 = nb3;
    cur ^= 1;
  }
#pragma unroll
  for (int f = 0; f < 8; f++)
#pragma unroll
    for (int ri = 0; ri < 4; ri++) {
      int r = mt + f*16 + kg*4 + ri;
      if (r < cnt) {
        int tok = sh ? r : tok_list[off + r];
        float* op = out + (size_t)tok * D_MODEL + c0;
        atomicAdd(op, ac0[f][ri]);
        atomicAdd(op + 16, ac1[f][ri]);
      }
    }
}

// ---------------- host ----------------
extern "C" void kernel_launch(void* const* d_in, const int* in_sizes, int n_in,
                              void* d_out, int out_size, void* d_ws, size_t ws_size,
                              hipStream_t stream) {
  const float* x     = (const float*)d_in[0];
  const float* fcos  = (const float*)d_in[1];
  const float* fsin  = (const float*)d_in[2];
  const float* anw   = (const float*)d_in[3];
  const float* fnw   = (const float*)d_in[4];
  const float* wq    = (const float*)d_in[5];
  const float* wk    = (const float*)d_in[6];
  const float* wvv   = (const float*)d_in[7];
  const float* wo    = (const float*)d_in[8];
  const float* qnw   = (const float*)d_in[9];
  const float* knw   = (const float*)d_in[10];
  const float* gatew = (const float*)d_in[11];
  const float* w1e   = (const float*)d_in[12];
  const float* w3e   = (const float*)d_in[13];
  const float* w2e   = (const float*)d_in[14];
  const float* sw1   = (const float*)d_in[15];
  const float* sw3   = (const float*)d_in[16];
  const float* sw2   = (const float*)d_in[17];
  float* out = (float*)d_out;

  char* ws = (char*)d_ws;
  const size_t MB = 1ull << 20;
  float*  hx    = (float*)(ws);             // 4MB (attn-norm out, then attn out)
  float*  h     = (float*)(ws + 4*MB);      // 4MB residual after attention
  float*  z     = (float*)(ws + 8*MB);      // 4MB ffn-norm out (f32, for gate)
  float*  qbuf  = (float*)(ws + 12*MB);     // 4MB (dead after attention)
  float*  kbuf  = (float*)(ws + 16*MB);     // 1MB
  float*  vbuf  = (float*)(ws + 17*MB);     // 1MB
  ushort* zb    = (ushort*)(ws + 12*MB);    // 2MB bf16 z (overlaps dead qbuf)
  ushort* gb    = (ushort*)(ws + 14*MB);    // 6.3MB bf16 expert activations
  ushort* s_gb  = (ushort*)(ws + 20*MB + 512*1024); // 1MB shared-expert act
  char*   misc  = ws + 22*MB;
  int*   sel      = (int*)(misc);
  float* topw     = (float*)(misc + 24576);
  int*   counts   = (int*)(misc + 49152);
  int*   offs     = (int*)(misc + 49408);
  int*   cursor   = (int*)(misc + 49664);
  int*   ntiles   = (int*)(misc + 50432);
  int*   tile2e   = (int*)(misc + 50688);
  int*   tile2mt  = (int*)(misc + 51200);
  int*   tok_list = (int*)(misc + 51712);
  float* wt_list  = (float*)(misc + 76288);

  // 1. attn rmsnorm
  rmsnorm_k<<<SEQ, 256, 0, stream>>>(x, anw, hx, nullptr);
  // 2. fused QKV projection (plain bf16)
  mfma_gemm_qkv<<<dim3(12, 64), 256, 0, stream>>>(hx, wq, wk, wvv, qbuf, kbuf, vbuf);
  // 3. q/k rmsnorm + rope
  qknorm_rope_k<<<dim3(SEQ, NHEADS + NKVH), 64, 0, stream>>>(qbuf, kbuf, qnw, knw, fcos, fsin);
  // 4. causal flash attention -> hx
  attn_mfma<<<dim3(SEQ / 64, NHEADS), 256, 0, stream>>>(qbuf, kbuf, vbuf, hx);
  // 5. o @ wo + x -> h (split-bf16, protects gate top-k; d_out = h)
  mfma_gemm_k<<<dim3(8, 64), 256, 0, stream>>>(hx, wo, h, out, x, 1024, 1024);
  // 6. ffn rmsnorm -> z (f32) + zb (bf16)
  rmsnorm_k<<<SEQ, 256, 0, stream>>>(h, fnw, z, zb);
  // 7. gate + top-k + bucketing + flattened tile list (incl. shared tiles)
  hipMemsetAsync(counts, 0, 256, stream);
  gate_topk_k<<<SEQ, 64, 0, stream>>>(z, gatew, sel, topw, counts);
  scan_k<<<1, 64, 0, stream>>>(counts, offs, cursor, tile2e, tile2mt, ntiles);
  scatter_k<<<SEQ / 256, 256, 0, stream>>>(sel, topw, cursor, tok_list, wt_list);
  // 8. MoE phase A (experts + shared expert in one dispatch)
  moe_up6<<<dim3(HEXP / 64, MAXTILES), 256, 0, stream>>>(zb, w1e, w3e,
      (size_t)D_MODEL * HEXP, sw1, sw3, gb, s_gb, tok_list, wt_list,
      counts, offs, tile2e, tile2mt, ntiles);
  // 9. MoE phase B (experts + shared expert in one dispatch)
  moe_down6<<<dim3(D_MODEL / 128, MAXTILES), 256, 0, stream>>>(gb, s_gb, w2e,
      (size_t)HEXP * D_MODEL, sw2, out, tok_list, counts, offs,
      tile2e, tile2mt, ntiles);
  (void)in_sizes; (void)n_in; (void)out_size; (void)ws_size;
}